// Round 1
// baseline (600.761 us; speedup 1.0000x reference)
//
#include <hip/hip_runtime.h>
#include <hip/hip_bf16.h>

typedef __attribute__((ext_vector_type(8))) short bf16x8;
typedef __attribute__((ext_vector_type(4))) float f32x4;
typedef unsigned short u16;

#define D_IN  1024
#define D_HID 4096
#define MROWS 16384   // B*T = 8*2048

// ---------- bf16 <-> f32 helpers (bit-exact RNE) ----------
__device__ __forceinline__ float b2f(u16 u) {
    union { unsigned int i; float f; } c; c.i = ((unsigned int)u) << 16; return c.f;
}
__device__ __forceinline__ u16 f2b(float f) {
    unsigned int u = __builtin_bit_cast(unsigned int, f);
    return (u16)((u + 0x7FFFu + ((u >> 16) & 1u)) >> 16);
}

// ---------- gamma = mean(|W|) + 1e-6 (two-stage reduction) ----------
__global__ void absmean_partial(const float* __restrict__ W, int n4, float* __restrict__ partials) {
    __shared__ float sdata[256];
    float s = 0.f;
    const int stride = gridDim.x * blockDim.x;
    for (int i = blockIdx.x * blockDim.x + threadIdx.x; i < n4; i += stride) {
        float4 v = ((const float4*)W)[i];
        s += fabsf(v.x) + fabsf(v.y) + fabsf(v.z) + fabsf(v.w);
    }
    sdata[threadIdx.x] = s;
    __syncthreads();
    for (int off = 128; off > 0; off >>= 1) {
        if (threadIdx.x < off) sdata[threadIdx.x] += sdata[threadIdx.x + off];
        __syncthreads();
    }
    if (threadIdx.x == 0) partials[blockIdx.x] = sdata[0];
}

__global__ void absmean_finalize(const float* __restrict__ partials, int nblocks, float inv_n,
                                 float* __restrict__ gamma) {
    __shared__ float sdata[256];
    float s = 0.f;
    for (int i = threadIdx.x; i < nblocks; i += 256) s += partials[i];
    sdata[threadIdx.x] = s;
    __syncthreads();
    for (int off = 128; off > 0; off >>= 1) {
        if (threadIdx.x < off) sdata[threadIdx.x] += sdata[threadIdx.x + off];
        __syncthreads();
    }
    if (threadIdx.x == 0) gamma[0] = sdata[0] * inv_n + 1e-6f;
}

// ---------- ternary quantize to bf16 {-1,0,+1} ----------
__global__ void quant_ternary(const float* __restrict__ W, const float* __restrict__ gamma,
                              u16* __restrict__ Wq, int n4) {
    const float thr = 0.5f * gamma[0];
    const int stride = gridDim.x * blockDim.x;
    for (int i = blockIdx.x * blockDim.x + threadIdx.x; i < n4; i += stride) {
        float4 v = ((const float4*)W)[i];
        ushort4 q;
        q.x = v.x > thr ? 0x3F80u : (v.x < -thr ? 0xBF80u : 0u);
        q.y = v.y > thr ? 0x3F80u : (v.y < -thr ? 0xBF80u : 0u);
        q.z = v.z > thr ? 0x3F80u : (v.z < -thr ? 0xBF80u : 0u);
        q.w = v.w > thr ? 0x3F80u : (v.w < -thr ? 0xBF80u : 0u);
        ((ushort4*)Wq)[i] = q;
    }
}

// ---------- cast x f32 -> bf16 ----------
__global__ void cast_to_bf16(const float* __restrict__ x, u16* __restrict__ xb, int n8) {
    const int stride = gridDim.x * blockDim.x;
    for (int i = blockIdx.x * blockDim.x + threadIdx.x; i < n8; i += stride) {
        float4 a = ((const float4*)x)[2 * i];
        float4 c = ((const float4*)x)[2 * i + 1];
        bf16x8 o;
        o[0] = (short)f2b(a.x); o[1] = (short)f2b(a.y); o[2] = (short)f2b(a.z); o[3] = (short)f2b(a.w);
        o[4] = (short)f2b(c.x); o[5] = (short)f2b(c.y); o[6] = (short)f2b(c.z); o[7] = (short)f2b(c.w);
        ((bf16x8*)xb)[i] = o;
    }
}

// ---------- GEMM: C[M,N] = A[M,K] @ B[N,K]^T, m97-style 128x128 tile ----------
// EPI 0: exact GELU epilogue, bf16 out.  EPI 1: raw f32 out.
template <int EPI>
__global__ __launch_bounds__(256, 2)
void gemm_bt(const u16* __restrict__ A, const u16* __restrict__ B,
             void* __restrict__ Cout, int M, int N, int K)
{
    constexpr int BM = 128, BN = 128, BK = 64;
    __shared__ u16 lA[BM * BK];
    __shared__ u16 lB[BN * BK];
    const int tid  = threadIdx.x;
    const int wave = tid >> 6, lane = tid & 63;
    const size_t m0 = (size_t)blockIdx.y * BM;
    const size_t n0 = (size_t)blockIdx.x * BN;
    const int wm = (wave >> 1) * 64, wn = (wave & 1) * 64;

    f32x4 acc[4][4];
#pragma unroll
    for (int i = 0; i < 4; ++i)
#pragma unroll
        for (int j = 0; j < 4; ++j) acc[i][j] = (f32x4){0.f, 0.f, 0.f, 0.f};

    const int row_s = tid >> 3;          // 0..31: staging row (per call c: +32*c)
    const int col_s = (tid & 7) * 8;     // element column within BK row
    const int nkt = K / BK;

    for (int kt = 0; kt < nkt; ++kt) {
        const u16* Ab = A + m0 * K + (size_t)kt * BK;
        const u16* Bb = B + n0 * K + (size_t)kt * BK;
#pragma unroll
        for (int c = 0; c < 4; ++c)
            __builtin_amdgcn_global_load_lds(
                (const __attribute__((address_space(1))) void*)(Ab + (size_t)(c * 32 + row_s) * K + col_s),
                (__attribute__((address_space(3))) void*)(lA + (c * 256 + wave * 64) * 8),
                16, 0, 0);
#pragma unroll
        for (int c = 0; c < 4; ++c)
            __builtin_amdgcn_global_load_lds(
                (const __attribute__((address_space(1))) void*)(Bb + (size_t)(c * 32 + row_s) * K + col_s),
                (__attribute__((address_space(3))) void*)(lB + (c * 256 + wave * 64) * 8),
                16, 0, 0);
        __syncthreads();
#pragma unroll
        for (int ks = 0; ks < 2; ++ks) {
            const int kb = ks * 32 + (lane >> 4) * 8;
            bf16x8 aF[4], bF[4];
#pragma unroll
            for (int i = 0; i < 4; ++i)
                aF[i] = *(const bf16x8*)(lA + (wm + i * 16 + (lane & 15)) * BK + kb);
#pragma unroll
            for (int j = 0; j < 4; ++j)
                bF[j] = *(const bf16x8*)(lB + (wn + j * 16 + (lane & 15)) * BK + kb);
#pragma unroll
            for (int i = 0; i < 4; ++i)
#pragma unroll
                for (int j = 0; j < 4; ++j)
                    acc[i][j] = __builtin_amdgcn_mfma_f32_16x16x32_bf16(aF[i], bF[j], acc[i][j], 0, 0, 0);
        }
        __syncthreads();
    }

    // C/D layout: col = lane&15, row = (lane>>4)*4 + r   [m89/m91]
    const int fr = (lane >> 4) * 4;
    const int fc = lane & 15;
    if constexpr (EPI == 0) {
        u16* C = (u16*)Cout;
#pragma unroll
        for (int i = 0; i < 4; ++i)
#pragma unroll
            for (int j = 0; j < 4; ++j)
#pragma unroll
                for (int r = 0; r < 4; ++r) {
                    size_t row = m0 + wm + i * 16 + fr + r;
                    size_t col = n0 + wn + j * 16 + fc;
                    float v = acc[i][j][r];
                    float g = 0.5f * v * (1.f + erff(v * 0.70710678118654752f));
                    C[row * (size_t)N + col] = f2b(g);
                }
    } else {
        float* C = (float*)Cout;
#pragma unroll
        for (int i = 0; i < 4; ++i)
#pragma unroll
            for (int j = 0; j < 4; ++j)
#pragma unroll
                for (int r = 0; r < 4; ++r) {
                    size_t row = m0 + wm + i * 16 + fr + r;
                    size_t col = n0 + wn + j * 16 + fc;
                    C[row * (size_t)N + col] = acc[i][j][r];
                }
    }
}

// ---------- in-place row LayerNorm over H=4096 (bf16 storage, f32 stats) ----------
__global__ __launch_bounds__(256)
void ln_rows(u16* __restrict__ h, const float* __restrict__ w, const float* __restrict__ b) {
    const int H = 4096;
    u16* row = h + (size_t)blockIdx.x * H;
    const int t = threadIdx.x;
    bf16x8 v0 = ((bf16x8*)row)[2 * t];
    bf16x8 v1 = ((bf16x8*)row)[2 * t + 1];
    float vals[16];
#pragma unroll
    for (int e = 0; e < 8; ++e) { vals[e] = b2f((u16)v0[e]); vals[8 + e] = b2f((u16)v1[e]); }
    float s = 0.f, ss = 0.f;
#pragma unroll
    for (int e = 0; e < 16; ++e) { s += vals[e]; ss += vals[e] * vals[e]; }
#pragma unroll
    for (int off = 32; off > 0; off >>= 1) {
        s  += __shfl_down(s, off);
        ss += __shfl_down(ss, off);
    }
    __shared__ float sh_s[4], sh_ss[4];
    const int wave = t >> 6, lane = t & 63;
    if (lane == 0) { sh_s[wave] = s; sh_ss[wave] = ss; }
    __syncthreads();
    s  = sh_s[0] + sh_s[1] + sh_s[2] + sh_s[3];
    ss = sh_ss[0] + sh_ss[1] + sh_ss[2] + sh_ss[3];
    const float mu = s * (1.f / 4096.f);
    const float var = ss * (1.f / 4096.f) - mu * mu;
    const float rstd = rsqrtf(var + 1e-5f);
    const int c0 = t * 16;
    bf16x8 o0, o1;
#pragma unroll
    for (int e = 0; e < 8; ++e) {
        o0[e] = (short)f2b((vals[e]     - mu) * rstd * w[c0 + e]     + b[c0 + e]);
        o1[e] = (short)f2b((vals[8 + e] - mu) * rstd * w[c0 + 8 + e] + b[c0 + 8 + e]);
    }
    ((bf16x8*)row)[2 * t]     = o0;
    ((bf16x8*)row)[2 * t + 1] = o1;
}

extern "C" void kernel_launch(void* const* d_in, const int* in_sizes, int n_in,
                              void* d_out, int out_size, void* d_ws, size_t ws_size,
                              hipStream_t stream)
{
    const float* x   = (const float*)d_in[0];
    const float* Wfc = (const float*)d_in[1];
    const float* lnw = (const float*)d_in[2];
    const float* lnb = (const float*)d_in[3];
    const float* Wpj = (const float*)d_in[4];
    float* out = (float*)d_out;
    char* ws = (char*)d_ws;

    u16* Wq_fc = (u16*)ws;                                   // 8 MiB
    u16* Wq_pj = (u16*)(ws + (size_t)(8u  << 20));           // 8 MiB
    u16* xb    = (u16*)(ws + (size_t)(16u << 20));           // 32 MiB
    u16* hbuf  = (u16*)(ws + (size_t)(48u << 20));           // 128 MiB
    float* tail = (float*)(ws + (size_t)(176u << 20));
    float* pfc = tail;
    float* ppj = tail + 1024;
    float* gfc = tail + 2048;
    float* gpj = tail + 2049;

    const int nW  = D_HID * D_IN;        // 4,194,304
    const int nW4 = nW / 4;

    absmean_partial<<<1024, 256, 0, stream>>>(Wfc, nW4, pfc);
    absmean_partial<<<1024, 256, 0, stream>>>(Wpj, nW4, ppj);
    absmean_finalize<<<1, 256, 0, stream>>>(pfc, 1024, 1.f / (float)nW, gfc);
    absmean_finalize<<<1, 256, 0, stream>>>(ppj, 1024, 1.f / (float)nW, gpj);
    quant_ternary<<<1024, 256, 0, stream>>>(Wfc, gfc, Wq_fc, nW4);
    quant_ternary<<<1024, 256, 0, stream>>>(Wpj, gpj, Wq_pj, nW4);

    const int nX8 = MROWS * D_IN / 8;    // 2,097,152
    cast_to_bf16<<<2048, 256, 0, stream>>>(x, xb, nX8);

    dim3 g1(D_HID / 128, MROWS / 128);   // (32, 128)
    gemm_bt<0><<<g1, 256, 0, stream>>>(xb, Wq_fc, hbuf, MROWS, D_HID, D_IN);

    ln_rows<<<MROWS, 256, 0, stream>>>(hbuf, lnw, lnb);

    dim3 g2(D_IN / 128, MROWS / 128);    // (8, 128)
    gemm_bt<1><<<g2, 256, 0, stream>>>(hbuf, Wq_pj, out, MROWS, D_IN, D_HID);
}

// Round 2
// 487.405 us; speedup vs baseline: 1.2326x; 1.2326x over previous
//
#include <hip/hip_runtime.h>
#include <hip/hip_bf16.h>

typedef __attribute__((ext_vector_type(8))) short bf16x8;
typedef __attribute__((ext_vector_type(4))) float f32x4;
typedef unsigned short u16;

#define D_IN  1024
#define D_HID 4096
#define MROWS 16384   // B*T = 8*2048

// ---------- bf16 <-> f32 helpers (bit-exact RNE) ----------
__device__ __forceinline__ float b2f(u16 u) {
    union { unsigned int i; float f; } c; c.i = ((unsigned int)u) << 16; return c.f;
}
__device__ __forceinline__ u16 f2b(float f) {
    unsigned int u = __builtin_bit_cast(unsigned int, f);
    return (u16)((u + 0x7FFFu + ((u >> 16) & 1u)) >> 16);
}

// ---------- gamma = mean(|W|) + 1e-6 (two-stage reduction) ----------
__global__ void absmean_partial(const float* __restrict__ W, int n4, float* __restrict__ partials) {
    __shared__ float sdata[256];
    float s = 0.f;
    const int stride = gridDim.x * blockDim.x;
    for (int i = blockIdx.x * blockDim.x + threadIdx.x; i < n4; i += stride) {
        float4 v = ((const float4*)W)[i];
        s += fabsf(v.x) + fabsf(v.y) + fabsf(v.z) + fabsf(v.w);
    }
    sdata[threadIdx.x] = s;
    __syncthreads();
    for (int off = 128; off > 0; off >>= 1) {
        if (threadIdx.x < off) sdata[threadIdx.x] += sdata[threadIdx.x + off];
        __syncthreads();
    }
    if (threadIdx.x == 0) partials[blockIdx.x] = sdata[0];
}

__global__ void absmean_finalize(const float* __restrict__ partials, int nblocks, float inv_n,
                                 float* __restrict__ gamma) {
    __shared__ float sdata[256];
    float s = 0.f;
    for (int i = threadIdx.x; i < nblocks; i += 256) s += partials[i];
    sdata[threadIdx.x] = s;
    __syncthreads();
    for (int off = 128; off > 0; off >>= 1) {
        if (threadIdx.x < off) sdata[threadIdx.x] += sdata[threadIdx.x + off];
        __syncthreads();
    }
    if (threadIdx.x == 0) gamma[0] = sdata[0] * inv_n + 1e-6f;
}

// ---------- ternary quantize to bf16 {-1,0,+1} ----------
__global__ void quant_ternary(const float* __restrict__ W, const float* __restrict__ gamma,
                              u16* __restrict__ Wq, int n4) {
    const float thr = 0.5f * gamma[0];
    const int stride = gridDim.x * blockDim.x;
    for (int i = blockIdx.x * blockDim.x + threadIdx.x; i < n4; i += stride) {
        float4 v = ((const float4*)W)[i];
        ushort4 q;
        q.x = v.x > thr ? 0x3F80u : (v.x < -thr ? 0xBF80u : 0u);
        q.y = v.y > thr ? 0x3F80u : (v.y < -thr ? 0xBF80u : 0u);
        q.z = v.z > thr ? 0x3F80u : (v.z < -thr ? 0xBF80u : 0u);
        q.w = v.w > thr ? 0x3F80u : (v.w < -thr ? 0xBF80u : 0u);
        ((ushort4*)Wq)[i] = q;
    }
}

// ---------- cast x f32 -> bf16 ----------
__global__ void cast_to_bf16(const float* __restrict__ x, u16* __restrict__ xb, int n8) {
    const int stride = gridDim.x * blockDim.x;
    for (int i = blockIdx.x * blockDim.x + threadIdx.x; i < n8; i += stride) {
        float4 a = ((const float4*)x)[2 * i];
        float4 c = ((const float4*)x)[2 * i + 1];
        bf16x8 o;
        o[0] = (short)f2b(a.x); o[1] = (short)f2b(a.y); o[2] = (short)f2b(a.z); o[3] = (short)f2b(a.w);
        o[4] = (short)f2b(c.x); o[5] = (short)f2b(c.y); o[6] = (short)f2b(c.z); o[7] = (short)f2b(c.w);
        ((bf16x8*)xb)[i] = o;
    }
}

// ==========================================================================
// 256x256 8-phase GEMM: C[M,N] = A[M,K] @ B[N,K]^T   (bf16 in, EPI epilogue)
// 8 waves (2M x 4N), BK=64, 128 KiB LDS double-buffered, st_16x32 swizzle,
// counted vmcnt(4) at phases 4/8, setprio around MFMA clusters, XCD swizzle.
// LDS byte map: A: buf*32768 + half*16384 + srow*2048 + scol*1024 + row*64 + cb
//               B: +65536. Swizzle: byte ^= ((row>>3)&1)<<5 (involution).
// ==========================================================================
template <int EPI>
__global__ __launch_bounds__(512, 2)
void gemm256(const u16* __restrict__ A, const u16* __restrict__ B,
             void* __restrict__ Cout, int M, int N, int K, int nbx)
{
    (void)M;
    __shared__ u16 lds[65536];           // 128 KiB
    char* const ldsc = (char*)lds;
    const int tid = threadIdx.x;
    const int w = tid >> 6, lane = tid & 63;

    // bijective XCD swizzle (nwg % 8 == 0 for our grids)
    const int nwg = (int)gridDim.x;
    const int qq = nwg >> 3;
    const int bid = (int)blockIdx.x;
    const int swz = (bid & 7) * qq + (bid >> 3);
    const int bx = swz % nbx, by = swz / nbx;
    const size_t m0 = (size_t)by * 256, n0 = (size_t)bx * 256;

    const int wm = (w >> 2) * 128;       // 0 or 128
    const int wn = (w & 3) * 64;         // 0,64,128,192

    // ---- staging constants: thread tid covers LDS bytes [tid*16,+16) of a half
    const int d0 = tid * 16;
    const int rrow = (d0 >> 6) & 15;
    const int sr0 = ((d0 >> 11) & 3) * 16 + rrow;                 // 0..63 (load1: +64)
    const int cbx = (d0 & 63) ^ (((rrow >> 3) & 1) << 5);         // inverse swizzle on source
    const int gc  = ((d0 >> 10) & 1) * 32 + (cbx >> 1);           // global element col 0..63

    // ---- fragment-read bases (swizzle folded into lane offset)
    const int laneoffsw = (((lane & 15) * 64) + ((lane >> 4) * 16)) ^ (((lane >> 3) & 1) << 5);
    const int aoff = ((wm >> 7) << 14) + laneoffsw;
    const int boff = 65536 + ((wn >> 7) << 14) + (((wn >> 4) & 7) << 11) + laneoffsw;

    f32x4 acc[8][4];
#pragma unroll
    for (int i = 0; i < 8; ++i)
#pragma unroll
        for (int j = 0; j < 4; ++j) acc[i][j] = (f32x4){0.f, 0.f, 0.f, 0.f};

    bf16x8 a[4][2], b[4][2];

#define STAGE_A(KT, BUFB, HH) do {                                                              \
    const u16* _s = A + (size_t)(m0 + (HH) * 128 + sr0) * K + (size_t)(KT) * 64 + gc;           \
    __builtin_amdgcn_global_load_lds((const __attribute__((address_space(1))) void*)_s,         \
        (__attribute__((address_space(3))) void*)(ldsc + (BUFB) * 32768 + (HH) * 16384 + w * 1024), 16, 0, 0); \
    __builtin_amdgcn_global_load_lds((const __attribute__((address_space(1))) void*)(_s + (size_t)64 * K), \
        (__attribute__((address_space(3))) void*)(ldsc + (BUFB) * 32768 + (HH) * 16384 + w * 1024 + 8192), 16, 0, 0); \
} while (0)

#define STAGE_B(KT, BUFB, HH) do {                                                              \
    const u16* _s = B + (size_t)(n0 + (HH) * 128 + sr0) * K + (size_t)(KT) * 64 + gc;           \
    __builtin_amdgcn_global_load_lds((const __attribute__((address_space(1))) void*)_s,         \
        (__attribute__((address_space(3))) void*)(ldsc + 65536 + (BUFB) * 32768 + (HH) * 16384 + w * 1024), 16, 0, 0); \
    __builtin_amdgcn_global_load_lds((const __attribute__((address_space(1))) void*)(_s + (size_t)64 * K), \
        (__attribute__((address_space(3))) void*)(ldsc + 65536 + (BUFB) * 32768 + (HH) * 16384 + w * 1024 + 8192), 16, 0, 0); \
} while (0)

#define RD_A(BUFB, S, KS) (*(const bf16x8*)(ldsc + (BUFB) * 32768 + aoff + ((S) << 11) + ((KS) << 10)))
#define RD_B(BUFB, S, KS) (*(const bf16x8*)(ldsc + (BUFB) * 32768 + boff + ((S) << 11) + ((KS) << 10)))

#define MM(MB, NB) do {                                                                         \
    _Pragma("unroll") for (int ii = 0; ii < 4; ++ii)                                            \
    _Pragma("unroll") for (int jj = 0; jj < 2; ++jj)                                            \
    _Pragma("unroll") for (int kk = 0; kk < 2; ++kk)                                            \
        acc[(MB) + ii][(NB) + jj] = __builtin_amdgcn_mfma_f32_16x16x32_bf16(                    \
            a[ii][kk], b[(NB) + jj][kk], acc[(MB) + ii][(NB) + jj], 0, 0, 0);                   \
} while (0)

#define BARR()  asm volatile("s_barrier" ::: "memory")
#define LGKM0() asm volatile("s_waitcnt lgkmcnt(0)" ::: "memory")

#define ITER(F) do {                                                                            \
    /* ph1: Q(0,0) of buf0; stage A-h0(t+1)->buf1 */                                            \
    _Pragma("unroll") for (int s = 0; s < 4; ++s) { a[s][0] = RD_A(0, s, 0); a[s][1] = RD_A(0, s, 1); } \
    _Pragma("unroll") for (int s = 0; s < 2; ++s) { b[s][0] = RD_B(0, s, 0); b[s][1] = RD_B(0, s, 1); } \
    STAGE_A(t + 1, 1, 0);                                                                       \
    asm volatile("s_waitcnt lgkmcnt(8)" ::: "memory");                                          \
    BARR(); LGKM0();                                                                            \
    __builtin_amdgcn_s_setprio(1); MM(0, 0); __builtin_amdgcn_s_setprio(0); BARR();             \
    /* ph2: Q(0,1); stage A-h1(t+1)->buf1 */                                                    \
    _Pragma("unroll") for (int s = 2; s < 4; ++s) { b[s][0] = RD_B(0, s, 0); b[s][1] = RD_B(0, s, 1); } \
    STAGE_A(t + 1, 1, 1);                                                                       \
    BARR(); LGKM0();                                                                            \
    __builtin_amdgcn_s_setprio(1); MM(0, 2); __builtin_amdgcn_s_setprio(0); BARR();             \
    /* ph3: Q(1,0); stage B-h0(t+2)->buf0 */                                                    \
    _Pragma("unroll") for (int s = 0; s < 4; ++s) { a[s][0] = RD_A(0, 4 + s, 0); a[s][1] = RD_A(0, 4 + s, 1); } \
    if (F) STAGE_B(t + 2, 0, 0);                                                                \
    BARR(); LGKM0();                                                                            \
    __builtin_amdgcn_s_setprio(1); MM(4, 0); __builtin_amdgcn_s_setprio(0); BARR();             \
    /* ph4: Q(1,1); stage B-h1(t+2)->buf0; counted drain for tile t+1 */                        \
    if (F) { STAGE_B(t + 2, 0, 1); asm volatile("s_waitcnt vmcnt(4)" ::: "memory"); }           \
    else   { asm volatile("s_waitcnt vmcnt(0)" ::: "memory"); }                                 \
    BARR();                                                                                     \
    __builtin_amdgcn_s_setprio(1); MM(4, 2); __builtin_amdgcn_s_setprio(0); BARR();             \
    /* ph5: Q(0,0) of buf1; stage A-h0(t+2)->buf0 */                                            \
    _Pragma("unroll") for (int s = 0; s < 4; ++s) { a[s][0] = RD_A(1, s, 0); a[s][1] = RD_A(1, s, 1); } \
    _Pragma("unroll") for (int s = 0; s < 2; ++s) { b[s][0] = RD_B(1, s, 0); b[s][1] = RD_B(1, s, 1); } \
    if (F) STAGE_A(t + 2, 0, 0);                                                                \
    asm volatile("s_waitcnt lgkmcnt(8)" ::: "memory");                                          \
    BARR(); LGKM0();                                                                            \
    __builtin_amdgcn_s_setprio(1); MM(0, 0); __builtin_amdgcn_s_setprio(0); BARR();             \
    /* ph6: Q(0,1); stage A-h1(t+2)->buf0 */                                                    \
    _Pragma("unroll") for (int s = 2; s < 4; ++s) { b[s][0] = RD_B(1, s, 0); b[s][1] = RD_B(1, s, 1); } \
    if (F) STAGE_A(t + 2, 0, 1);                                                                \
    BARR(); LGKM0();                                                                            \
    __builtin_amdgcn_s_setprio(1); MM(0, 2); __builtin_amdgcn_s_setprio(0); BARR();             \
    /* ph7: Q(1,0); stage B-h0(t+3)->buf1 */                                                    \
    _Pragma("unroll") for (int s = 0; s < 4; ++s) { a[s][0] = RD_A(1, 4 + s, 0); a[s][1] = RD_A(1, 4 + s, 1); } \
    if (F) STAGE_B(t + 3, 1, 0);                                                                \
    BARR(); LGKM0();                                                                            \
    __builtin_amdgcn_s_setprio(1); MM(4, 0); __builtin_amdgcn_s_setprio(0); BARR();             \
    /* ph8: Q(1,1); stage B-h1(t+3)->buf1; counted drain for tile t+2 */                        \
    if (F) { STAGE_B(t + 3, 1, 1); asm volatile("s_waitcnt vmcnt(4)" ::: "memory"); }           \
    BARR();                                                                                     \
    __builtin_amdgcn_s_setprio(1); MM(4, 2); __builtin_amdgcn_s_setprio(0); BARR();             \
} while (0)

    const int nkt = K >> 6;
    const int niter = nkt >> 1;          // >= 2 for our shapes (8 or 32)

    // prologue: tile0 -> buf0 (4 halves), tile1 B-halves -> buf1
    STAGE_A(0, 0, 0);
    STAGE_A(0, 0, 1);
    STAGE_B(0, 0, 0);
    STAGE_B(0, 0, 1);
    STAGE_B(1, 1, 0);
    STAGE_B(1, 1, 1);
    asm volatile("s_waitcnt vmcnt(4)" ::: "memory");   // tile0 fully arrived
    BARR();

    for (int it = 0; it + 1 < niter; ++it) { const int t = 2 * it; ITER(1); }
    { const int t = 2 * (niter - 1); ITER(0); }

    // ---- epilogue: C/D layout col = lane&15, row = (lane>>4)*4 + r
    const int fr = (lane >> 4) * 4;
    const int fc = lane & 15;
    if constexpr (EPI == 0) {
        u16* C = (u16*)Cout;
#pragma unroll
        for (int mf = 0; mf < 8; ++mf)
#pragma unroll
            for (int nf = 0; nf < 4; ++nf)
#pragma unroll
                for (int r = 0; r < 4; ++r) {
                    size_t row = m0 + wm + mf * 16 + fr + r;
                    size_t col = n0 + wn + nf * 16 + fc;
                    float v = acc[mf][nf][r];
                    float g = 0.5f * v * (1.f + erff(v * 0.70710678118654752f));
                    C[row * (size_t)N + col] = f2b(g);
                }
    } else {
        float* C = (float*)Cout;
#pragma unroll
        for (int mf = 0; mf < 8; ++mf)
#pragma unroll
            for (int nf = 0; nf < 4; ++nf)
#pragma unroll
                for (int r = 0; r < 4; ++r) {
                    size_t row = m0 + wm + mf * 16 + fr + r;
                    size_t col = n0 + wn + nf * 16 + fc;
                    C[row * (size_t)N + col] = acc[mf][nf][r];
                }
    }
#undef STAGE_A
#undef STAGE_B
#undef RD_A
#undef RD_B
#undef MM
#undef BARR
#undef LGKM0
#undef ITER
}

// ---------- in-place row LayerNorm over H=4096 (bf16 storage, f32 stats) ----------
__global__ __launch_bounds__(256)
void ln_rows(u16* __restrict__ h, const float* __restrict__ w, const float* __restrict__ b) {
    const int H = 4096;
    u16* row = h + (size_t)blockIdx.x * H;
    const int t = threadIdx.x;
    bf16x8 v0 = ((bf16x8*)row)[2 * t];
    bf16x8 v1 = ((bf16x8*)row)[2 * t + 1];
    float vals[16];
#pragma unroll
    for (int e = 0; e < 8; ++e) { vals[e] = b2f((u16)v0[e]); vals[8 + e] = b2f((u16)v1[e]); }
    float s = 0.f, ss = 0.f;
#pragma unroll
    for (int e = 0; e < 16; ++e) { s += vals[e]; ss += vals[e] * vals[e]; }
#pragma unroll
    for (int off = 32; off > 0; off >>= 1) {
        s  += __shfl_down(s, off);
        ss += __shfl_down(ss, off);
    }
    __shared__ float sh_s[4], sh_ss[4];
    const int wave = t >> 6, lane = t & 63;
    if (lane == 0) { sh_s[wave] = s; sh_ss[wave] = ss; }
    __syncthreads();
    s  = sh_s[0] + sh_s[1] + sh_s[2] + sh_s[3];
    ss = sh_ss[0] + sh_ss[1] + sh_ss[2] + sh_ss[3];
    const float mu = s * (1.f / 4096.f);
    const float var = ss * (1.f / 4096.f) - mu * mu;
    const float rstd = rsqrtf(var + 1e-5f);
    const int c0 = t * 16;
    bf16x8 o0, o1;
#pragma unroll
    for (int e = 0; e < 8; ++e) {
        o0[e] = (short)f2b((vals[e]     - mu) * rstd * w[c0 + e]     + b[c0 + e]);
        o1[e] = (short)f2b((vals[8 + e] - mu) * rstd * w[c0 + 8 + e] + b[c0 + 8 + e]);
    }
    ((bf16x8*)row)[2 * t]     = o0;
    ((bf16x8*)row)[2 * t + 1] = o1;
}

extern "C" void kernel_launch(void* const* d_in, const int* in_sizes, int n_in,
                              void* d_out, int out_size, void* d_ws, size_t ws_size,
                              hipStream_t stream)
{
    const float* x   = (const float*)d_in[0];
    const float* Wfc = (const float*)d_in[1];
    const float* lnw = (const float*)d_in[2];
    const float* lnb = (const float*)d_in[3];
    const float* Wpj = (const float*)d_in[4];
    float* out = (float*)d_out;
    char* ws = (char*)d_ws;

    u16* Wq_fc = (u16*)ws;                                   // 8 MiB
    u16* Wq_pj = (u16*)(ws + (size_t)(8u  << 20));           // 8 MiB
    u16* xb    = (u16*)(ws + (size_t)(16u << 20));           // 32 MiB
    u16* hbuf  = (u16*)(ws + (size_t)(48u << 20));           // 128 MiB
    float* tail = (float*)(ws + (size_t)(176u << 20));
    float* pfc = tail;
    float* ppj = tail + 1024;
    float* gfc = tail + 2048;
    float* gpj = tail + 2049;

    const int nW  = D_HID * D_IN;        // 4,194,304
    const int nW4 = nW / 4;

    absmean_partial<<<1024, 256, 0, stream>>>(Wfc, nW4, pfc);
    absmean_partial<<<1024, 256, 0, stream>>>(Wpj, nW4, ppj);
    absmean_finalize<<<1, 256, 0, stream>>>(pfc, 1024, 1.f / (float)nW, gfc);
    absmean_finalize<<<1, 256, 0, stream>>>(ppj, 1024, 1.f / (float)nW, gpj);
    quant_ternary<<<1024, 256, 0, stream>>>(Wfc, gfc, Wq_fc, nW4);
    quant_ternary<<<1024, 256, 0, stream>>>(Wpj, gpj, Wq_pj, nW4);

    const int nX8 = MROWS * D_IN / 8;    // 2,097,152
    cast_to_bf16<<<2048, 256, 0, stream>>>(x, xb, nX8);

    // GEMM1: [16384,1024] x [4096,1024]^T -> GELU -> bf16 [16384,4096]
    {
        const int nbx = D_HID / 256;     // 16
        const int nby = MROWS / 256;     // 64
        gemm256<0><<<dim3(nbx * nby), dim3(512), 0, stream>>>(xb, Wq_fc, hbuf, MROWS, D_HID, D_IN, nbx);
    }

    ln_rows<<<MROWS, 256, 0, stream>>>(hbuf, lnw, lnb);

    // GEMM2: [16384,4096] x [1024,4096]^T -> f32 [16384,1024]
    {
        const int nbx = D_IN / 256;      // 4
        const int nby = MROWS / 256;     // 64
        gemm256<1><<<dim3(nbx * nby), dim3(512), 0, stream>>>(hbuf, Wq_pj, out, MROWS, D_IN, D_HID, nbx);
    }
}

// Round 3
// 426.185 us; speedup vs baseline: 1.4096x; 1.1436x over previous
//
#include <hip/hip_runtime.h>
#include <hip/hip_bf16.h>

typedef __attribute__((ext_vector_type(8))) short bf16x8;
typedef __attribute__((ext_vector_type(4))) float f32x4;
typedef unsigned short u16;

#define D_IN  1024
#define D_HID 4096
#define MROWS 16384   // B*T = 8*2048

// ---------- bf16 <-> f32 helpers (bit-exact RNE) ----------
__device__ __forceinline__ float b2f(u16 u) {
    union { unsigned int i; float f; } c; c.i = ((unsigned int)u) << 16; return c.f;
}
__device__ __forceinline__ u16 f2b(float f) {
    unsigned int u = __builtin_bit_cast(unsigned int, f);
    return (u16)((u + 0x7FFFu + ((u >> 16) & 1u)) >> 16);
}

// ---------- fast branchless GELU (tanh form, err<=3e-3 abs, << bf16 step) ----
__device__ __forceinline__ float gelu_fast(float v) {
    // v * sigmoid(1.5957691*(v + 0.044715 v^3)) ; exp2-based, saturates cleanly
    float p = v * fmaf(0.044715f * v, v, 1.0f);
    float e = __builtin_amdgcn_exp2f(-2.302202983f * p);
    return v * __builtin_amdgcn_rcpf(1.0f + e);
}

// ---------- gamma = mean(|W|) + 1e-6 (two weights per launch) ----------
__global__ void absmean_partial2(const float* __restrict__ W0, const float* __restrict__ W1,
                                 int n4, float* __restrict__ partials) {
    const float* W = blockIdx.y ? W1 : W0;
    float* out = partials + blockIdx.y * 1024;
    __shared__ float sdata[256];
    float s = 0.f;
    const int stride = gridDim.x * blockDim.x;
    for (int i = blockIdx.x * blockDim.x + threadIdx.x; i < n4; i += stride) {
        float4 v = ((const float4*)W)[i];
        s += fabsf(v.x) + fabsf(v.y) + fabsf(v.z) + fabsf(v.w);
    }
    sdata[threadIdx.x] = s;
    __syncthreads();
    for (int off = 128; off > 0; off >>= 1) {
        if (threadIdx.x < off) sdata[threadIdx.x] += sdata[threadIdx.x + off];
        __syncthreads();
    }
    if (threadIdx.x == 0) out[blockIdx.x] = sdata[0];
}

__global__ void absmean_finalize2(const float* __restrict__ partials, float inv_n,
                                  float* __restrict__ gamma) {
    const float* p = partials + blockIdx.x * 1024;
    __shared__ float sdata[256];
    float s = 0.f;
    for (int i = threadIdx.x; i < 1024; i += 256) s += p[i];
    sdata[threadIdx.x] = s;
    __syncthreads();
    for (int off = 128; off > 0; off >>= 1) {
        if (threadIdx.x < off) sdata[threadIdx.x] += sdata[threadIdx.x + off];
        __syncthreads();
    }
    if (threadIdx.x == 0) gamma[blockIdx.x] = sdata[0] * inv_n + 1e-6f;
}

// ---------- ternary quantize to bf16 {-1,0,+1}, both weights ----------
__global__ void quant_ternary2(const float* __restrict__ W0, const float* __restrict__ W1,
                               const float* __restrict__ gamma,
                               u16* __restrict__ Q0, u16* __restrict__ Q1, int n4) {
    const float* W = blockIdx.y ? W1 : W0;
    u16* Wq = blockIdx.y ? Q1 : Q0;
    const float thr = 0.5f * gamma[blockIdx.y];
    const int stride = gridDim.x * blockDim.x;
    for (int i = blockIdx.x * blockDim.x + threadIdx.x; i < n4; i += stride) {
        float4 v = ((const float4*)W)[i];
        ushort4 q;
        q.x = v.x > thr ? 0x3F80u : (v.x < -thr ? 0xBF80u : 0u);
        q.y = v.y > thr ? 0x3F80u : (v.y < -thr ? 0xBF80u : 0u);
        q.z = v.z > thr ? 0x3F80u : (v.z < -thr ? 0xBF80u : 0u);
        q.w = v.w > thr ? 0x3F80u : (v.w < -thr ? 0xBF80u : 0u);
        ((ushort4*)Wq)[i] = q;
    }
}

// ---------- cast x f32 -> bf16 ----------
__global__ void cast_to_bf16(const float* __restrict__ x, u16* __restrict__ xb, int n8) {
    const int stride = gridDim.x * blockDim.x;
    for (int i = blockIdx.x * blockDim.x + threadIdx.x; i < n8; i += stride) {
        float4 a = ((const float4*)x)[2 * i];
        float4 c = ((const float4*)x)[2 * i + 1];
        bf16x8 o;
        o[0] = (short)f2b(a.x); o[1] = (short)f2b(a.y); o[2] = (short)f2b(a.z); o[3] = (short)f2b(a.w);
        o[4] = (short)f2b(c.x); o[5] = (short)f2b(c.y); o[6] = (short)f2b(c.z); o[7] = (short)f2b(c.w);
        ((bf16x8*)xb)[i] = o;
    }
}

// ==========================================================================
// 256x256 8-phase GEMM: C[M,N] = A[M,K] @ B[N,K]^T   (bf16 in, EPI epilogue)
// 8 waves (2M x 4N), BK=64, 128 KiB LDS double-buffered, st_16x32 swizzle,
// counted vmcnt(4) at phases 4/8, setprio around MFMA clusters, XCD swizzle.
// ==========================================================================
template <int EPI>
__global__ __launch_bounds__(512, 2)
void gemm256(const u16* __restrict__ A, const u16* __restrict__ B,
             void* __restrict__ Cout, int M, int N, int K, int nbx)
{
    (void)M;
    __shared__ u16 lds[65536];           // 128 KiB
    char* const ldsc = (char*)lds;
    const int tid = threadIdx.x;
    const int w = tid >> 6, lane = tid & 63;

    // bijective XCD swizzle (nwg % 8 == 0 for our grids)
    const int nwg = (int)gridDim.x;
    const int qq = nwg >> 3;
    const int bid = (int)blockIdx.x;
    const int swz = (bid & 7) * qq + (bid >> 3);
    const int bx = swz % nbx, by = swz / nbx;
    const size_t m0 = (size_t)by * 256, n0 = (size_t)bx * 256;

    const int wm = (w >> 2) * 128;       // 0 or 128
    const int wn = (w & 3) * 64;         // 0,64,128,192

    // ---- staging constants: thread tid covers LDS bytes [tid*16,+16) of a half
    const int d0 = tid * 16;
    const int rrow = (d0 >> 6) & 15;
    const int sr0 = ((d0 >> 11) & 3) * 16 + rrow;                 // 0..63 (load1: +64)
    const int cbx = (d0 & 63) ^ (((rrow >> 3) & 1) << 5);         // inverse swizzle on source
    const int gc  = ((d0 >> 10) & 1) * 32 + (cbx >> 1);           // global element col 0..63

    // ---- fragment-read bases (swizzle folded into lane offset)
    const int laneoffsw = (((lane & 15) * 64) + ((lane >> 4) * 16)) ^ (((lane >> 3) & 1) << 5);
    const int aoff = ((wm >> 7) << 14) + laneoffsw;
    const int boff = 65536 + ((wn >> 7) << 14) + (((wn >> 4) & 7) << 11) + laneoffsw;

    f32x4 acc[8][4];
#pragma unroll
    for (int i = 0; i < 8; ++i)
#pragma unroll
        for (int j = 0; j < 4; ++j) acc[i][j] = (f32x4){0.f, 0.f, 0.f, 0.f};

    bf16x8 a[4][2], b[4][2];

#define STAGE_A(KT, BUFB, HH) do {                                                              \
    const u16* _s = A + (size_t)(m0 + (HH) * 128 + sr0) * K + (size_t)(KT) * 64 + gc;           \
    __builtin_amdgcn_global_load_lds((const __attribute__((address_space(1))) void*)_s,         \
        (__attribute__((address_space(3))) void*)(ldsc + (BUFB) * 32768 + (HH) * 16384 + w * 1024), 16, 0, 0); \
    __builtin_amdgcn_global_load_lds((const __attribute__((address_space(1))) void*)(_s + (size_t)64 * K), \
        (__attribute__((address_space(3))) void*)(ldsc + (BUFB) * 32768 + (HH) * 16384 + w * 1024 + 8192), 16, 0, 0); \
} while (0)

#define STAGE_B(KT, BUFB, HH) do {                                                              \
    const u16* _s = B + (size_t)(n0 + (HH) * 128 + sr0) * K + (size_t)(KT) * 64 + gc;           \
    __builtin_amdgcn_global_load_lds((const __attribute__((address_space(1))) void*)_s,         \
        (__attribute__((address_space(3))) void*)(ldsc + 65536 + (BUFB) * 32768 + (HH) * 16384 + w * 1024), 16, 0, 0); \
    __builtin_amdgcn_global_load_lds((const __attribute__((address_space(1))) void*)(_s + (size_t)64 * K), \
        (__attribute__((address_space(3))) void*)(ldsc + 65536 + (BUFB) * 32768 + (HH) * 16384 + w * 1024 + 8192), 16, 0, 0); \
} while (0)

#define RD_A(BUFB, S, KS) (*(const bf16x8*)(ldsc + (BUFB) * 32768 + aoff + ((S) << 11) + ((KS) << 10)))
#define RD_B(BUFB, S, KS) (*(const bf16x8*)(ldsc + (BUFB) * 32768 + boff + ((S) << 11) + ((KS) << 10)))

#define MM(MB, NB) do {                                                                         \
    _Pragma("unroll") for (int ii = 0; ii < 4; ++ii)                                            \
    _Pragma("unroll") for (int jj = 0; jj < 2; ++jj)                                            \
    _Pragma("unroll") for (int kk = 0; kk < 2; ++kk)                                            \
        acc[(MB) + ii][(NB) + jj] = __builtin_amdgcn_mfma_f32_16x16x32_bf16(                    \
            a[ii][kk], b[(NB) + jj][kk], acc[(MB) + ii][(NB) + jj], 0, 0, 0);                   \
} while (0)

#define BARR()  asm volatile("s_barrier" ::: "memory")
#define LGKM0() asm volatile("s_waitcnt lgkmcnt(0)" ::: "memory")

#define ITER(F) do {                                                                            \
    /* ph1: Q(0,0) of buf0; stage A-h0(t+1)->buf1 */                                            \
    _Pragma("unroll") for (int s = 0; s < 4; ++s) { a[s][0] = RD_A(0, s, 0); a[s][1] = RD_A(0, s, 1); } \
    _Pragma("unroll") for (int s = 0; s < 2; ++s) { b[s][0] = RD_B(0, s, 0); b[s][1] = RD_B(0, s, 1); } \
    STAGE_A(t + 1, 1, 0);                                                                       \
    asm volatile("s_waitcnt lgkmcnt(8)" ::: "memory");                                          \
    BARR(); LGKM0();                                                                            \
    __builtin_amdgcn_s_setprio(1); MM(0, 0); __builtin_amdgcn_s_setprio(0); BARR();             \
    /* ph2: Q(0,1); stage A-h1(t+1)->buf1 */                                                    \
    _Pragma("unroll") for (int s = 2; s < 4; ++s) { b[s][0] = RD_B(0, s, 0); b[s][1] = RD_B(0, s, 1); } \
    STAGE_A(t + 1, 1, 1);                                                                       \
    BARR(); LGKM0();                                                                            \
    __builtin_amdgcn_s_setprio(1); MM(0, 2); __builtin_amdgcn_s_setprio(0); BARR();             \
    /* ph3: Q(1,0); stage B-h0(t+2)->buf0 */                                                    \
    _Pragma("unroll") for (int s = 0; s < 4; ++s) { a[s][0] = RD_A(0, 4 + s, 0); a[s][1] = RD_A(0, 4 + s, 1); } \
    if (F) STAGE_B(t + 2, 0, 0);                                                                \
    BARR(); LGKM0();                                                                            \
    __builtin_amdgcn_s_setprio(1); MM(4, 0); __builtin_amdgcn_s_setprio(0); BARR();             \
    /* ph4: Q(1,1); stage B-h1(t+2)->buf0; counted drain for tile t+1 */                        \
    if (F) { STAGE_B(t + 2, 0, 1); asm volatile("s_waitcnt vmcnt(4)" ::: "memory"); }           \
    else   { asm volatile("s_waitcnt vmcnt(0)" ::: "memory"); }                                 \
    BARR();                                                                                     \
    __builtin_amdgcn_s_setprio(1); MM(4, 2); __builtin_amdgcn_s_setprio(0); BARR();             \
    /* ph5: Q(0,0) of buf1; stage A-h0(t+2)->buf0 */                                            \
    _Pragma("unroll") for (int s = 0; s < 4; ++s) { a[s][0] = RD_A(1, s, 0); a[s][1] = RD_A(1, s, 1); } \
    _Pragma("unroll") for (int s = 0; s < 2; ++s) { b[s][0] = RD_B(1, s, 0); b[s][1] = RD_B(1, s, 1); } \
    if (F) STAGE_A(t + 2, 0, 0);                                                                \
    asm volatile("s_waitcnt lgkmcnt(8)" ::: "memory");                                          \
    BARR(); LGKM0();                                                                            \
    __builtin_amdgcn_s_setprio(1); MM(0, 0); __builtin_amdgcn_s_setprio(0); BARR();             \
    /* ph6: Q(0,1); stage A-h1(t+2)->buf0 */                                                    \
    _Pragma("unroll") for (int s = 2; s < 4; ++s) { b[s][0] = RD_B(1, s, 0); b[s][1] = RD_B(1, s, 1); } \
    if (F) STAGE_A(t + 2, 0, 1);                                                                \
    BARR(); LGKM0();                                                                            \
    __builtin_amdgcn_s_setprio(1); MM(0, 2); __builtin_amdgcn_s_setprio(0); BARR();             \
    /* ph7: Q(1,0); stage B-h0(t+3)->buf1 */                                                    \
    _Pragma("unroll") for (int s = 0; s < 4; ++s) { a[s][0] = RD_A(1, 4 + s, 0); a[s][1] = RD_A(1, 4 + s, 1); } \
    if (F) STAGE_B(t + 3, 1, 0);                                                                \
    BARR(); LGKM0();                                                                            \
    __builtin_amdgcn_s_setprio(1); MM(4, 0); __builtin_amdgcn_s_setprio(0); BARR();             \
    /* ph8: Q(1,1); stage B-h1(t+3)->buf1; counted drain for tile t+2 */                        \
    if (F) { STAGE_B(t + 3, 1, 1); asm volatile("s_waitcnt vmcnt(4)" ::: "memory"); }           \
    BARR();                                                                                     \
    __builtin_amdgcn_s_setprio(1); MM(4, 2); __builtin_amdgcn_s_setprio(0); BARR();             \
} while (0)

    const int nkt = K >> 6;
    const int niter = nkt >> 1;          // >= 2 for our shapes (8 or 32)

    // prologue: tile0 -> buf0 (4 halves), tile1 B-halves -> buf1
    STAGE_A(0, 0, 0);
    STAGE_A(0, 0, 1);
    STAGE_B(0, 0, 0);
    STAGE_B(0, 0, 1);
    STAGE_B(1, 1, 0);
    STAGE_B(1, 1, 1);
    asm volatile("s_waitcnt vmcnt(4)" ::: "memory");   // tile0 fully arrived
    BARR();

    for (int it = 0; it + 1 < niter; ++it) { const int t = 2 * it; ITER(1); }
    { const int t = 2 * (niter - 1); ITER(0); }

    // ---- epilogue: C/D layout col = lane&15, row = (lane>>4)*4 + r
    const int fr = (lane >> 4) * 4;
    const int fc = lane & 15;
    if constexpr (EPI == 0) {
        u16* C = (u16*)Cout;
#pragma unroll
        for (int mf = 0; mf < 8; ++mf)
#pragma unroll
            for (int nf = 0; nf < 4; ++nf)
#pragma unroll
                for (int r = 0; r < 4; ++r) {
                    size_t row = m0 + wm + mf * 16 + fr + r;
                    size_t col = n0 + wn + nf * 16 + fc;
                    C[row * (size_t)N + col] = f2b(gelu_fast(acc[mf][nf][r]));
                }
    } else {
        float* C = (float*)Cout;
#pragma unroll
        for (int mf = 0; mf < 8; ++mf)
#pragma unroll
            for (int nf = 0; nf < 4; ++nf)
#pragma unroll
                for (int r = 0; r < 4; ++r) {
                    size_t row = m0 + wm + mf * 16 + fr + r;
                    size_t col = n0 + wn + nf * 16 + fc;
                    C[row * (size_t)N + col] = acc[mf][nf][r];
                }
    }
#undef STAGE_A
#undef STAGE_B
#undef RD_A
#undef RD_B
#undef MM
#undef BARR
#undef LGKM0
#undef ITER
}

// ---------- in-place row LayerNorm over H=4096 (bf16 storage, f32 stats) ----------
__global__ __launch_bounds__(256)
void ln_rows(u16* __restrict__ h, const float* __restrict__ w, const float* __restrict__ b) {
    const int H = 4096;
    u16* row = h + (size_t)blockIdx.x * H;
    const int t = threadIdx.x;
    bf16x8 v0 = ((bf16x8*)row)[2 * t];
    bf16x8 v1 = ((bf16x8*)row)[2 * t + 1];
    float vals[16];
#pragma unroll
    for (int e = 0; e < 8; ++e) { vals[e] = b2f((u16)v0[e]); vals[8 + e] = b2f((u16)v1[e]); }
    float s = 0.f, ss = 0.f;
#pragma unroll
    for (int e = 0; e < 16; ++e) { s += vals[e]; ss += vals[e] * vals[e]; }
#pragma unroll
    for (int off = 32; off > 0; off >>= 1) {
        s  += __shfl_down(s, off);
        ss += __shfl_down(ss, off);
    }
    __shared__ float sh_s[4], sh_ss[4];
    const int wave = t >> 6, lane = t & 63;
    if (lane == 0) { sh_s[wave] = s; sh_ss[wave] = ss; }
    __syncthreads();
    s  = sh_s[0] + sh_s[1] + sh_s[2] + sh_s[3];
    ss = sh_ss[0] + sh_ss[1] + sh_ss[2] + sh_ss[3];
    const float mu = s * (1.f / 4096.f);
    const float var = ss * (1.f / 4096.f) - mu * mu;
    const float rstd = rsqrtf(var + 1e-5f);
    const int c0 = t * 16;
    bf16x8 o0, o1;
#pragma unroll
    for (int e = 0; e < 8; ++e) {
        o0[e] = (short)f2b((vals[e]     - mu) * rstd * w[c0 + e]     + b[c0 + e]);
        o1[e] = (short)f2b((vals[8 + e] - mu) * rstd * w[c0 + 8 + e] + b[c0 + 8 + e]);
    }
    ((bf16x8*)row)[2 * t]     = o0;
    ((bf16x8*)row)[2 * t + 1] = o1;
}

extern "C" void kernel_launch(void* const* d_in, const int* in_sizes, int n_in,
                              void* d_out, int out_size, void* d_ws, size_t ws_size,
                              hipStream_t stream)
{
    const float* x   = (const float*)d_in[0];
    const float* Wfc = (const float*)d_in[1];
    const float* lnw = (const float*)d_in[2];
    const float* lnb = (const float*)d_in[3];
    const float* Wpj = (const float*)d_in[4];
    float* out = (float*)d_out;
    char* ws = (char*)d_ws;

    u16* Wq_fc = (u16*)ws;                                   // 8 MiB
    u16* Wq_pj = (u16*)(ws + (size_t)(8u  << 20));           // 8 MiB
    u16* xb    = (u16*)(ws + (size_t)(16u << 20));           // 32 MiB
    u16* hbuf  = (u16*)(ws + (size_t)(48u << 20));           // 128 MiB
    float* tail = (float*)(ws + (size_t)(176u << 20));
    float* parts = tail;                                     // 2 x 1024
    float* gam   = tail + 2048;                              // 2

    const int nW  = D_HID * D_IN;        // 4,194,304
    const int nW4 = nW / 4;

    absmean_partial2<<<dim3(1024, 2), 256, 0, stream>>>(Wfc, Wpj, nW4, parts);
    absmean_finalize2<<<2, 256, 0, stream>>>(parts, 1.f / (float)nW, gam);
    quant_ternary2<<<dim3(1024, 2), 256, 0, stream>>>(Wfc, Wpj, gam, Wq_fc, Wq_pj, nW4);

    const int nX8 = MROWS * D_IN / 8;    // 2,097,152
    cast_to_bf16<<<2048, 256, 0, stream>>>(x, xb, nX8);

    // GEMM1: [16384,1024] x [4096,1024]^T -> GELU -> bf16 [16384,4096]
    {
        const int nbx = D_HID / 256;     // 16
        const int nby = MROWS / 256;     // 64
        gemm256<0><<<dim3(nbx * nby), dim3(512), 0, stream>>>(xb, Wq_fc, hbuf, MROWS, D_HID, D_IN, nbx);
    }

    ln_rows<<<MROWS, 256, 0, stream>>>(hbuf, lnw, lnb);

    // GEMM2: [16384,4096] x [1024,4096]^T -> f32 [16384,1024]
    {
        const int nbx = D_IN / 256;      // 4
        const int nby = MROWS / 256;     // 64
        gemm256<1><<<dim3(nbx * nby), dim3(512), 0, stream>>>(hbuf, Wq_pj, out, MROWS, D_IN, D_HID, nbx);
    }
}

// Round 5
// 411.093 us; speedup vs baseline: 1.4614x; 1.0367x over previous
//
#include <hip/hip_runtime.h>
#include <hip/hip_bf16.h>

typedef __attribute__((ext_vector_type(8))) short bf16x8;
typedef __attribute__((ext_vector_type(4))) float f32x4;
typedef unsigned short u16;

#define D_IN  1024
#define D_HID 4096
#define MROWS 16384   // B*T = 8*2048

// ---------- bf16 <-> f32 helpers (bit-exact RNE) ----------
__device__ __forceinline__ float b2f(u16 u) {
    union { unsigned int i; float f; } c; c.i = ((unsigned int)u) << 16; return c.f;
}
__device__ __forceinline__ u16 f2b(float f) {
    unsigned int u = __builtin_bit_cast(unsigned int, f);
    return (u16)((u + 0x7FFFu + ((u >> 16) & 1u)) >> 16);
}

// ---------- fast branchless GELU (tanh form, err<=3e-3 abs, << bf16 step) ----
__device__ __forceinline__ float gelu_fast(float v) {
    float p = v * fmaf(0.044715f * v, v, 1.0f);
    float e = __builtin_amdgcn_exp2f(-2.302202983f * p);
    return v * __builtin_amdgcn_rcpf(1.0f + e);
}

// ---------- prep1: absmean partials for both W (y=0,1) + cast x->bf16 (y=2) ----
__global__ void prep1(const float* __restrict__ x, const float* __restrict__ W0,
                      const float* __restrict__ W1, u16* __restrict__ xb,
                      float* __restrict__ partials, int n4, int n8) {
    const int y = blockIdx.y;
    if (y == 2) {
        const int stride = gridDim.x * blockDim.x;
        for (int i = blockIdx.x * blockDim.x + threadIdx.x; i < n8; i += stride) {
            float4 a = ((const float4*)x)[2 * i];
            float4 c = ((const float4*)x)[2 * i + 1];
            bf16x8 o;
            o[0] = (short)f2b(a.x); o[1] = (short)f2b(a.y); o[2] = (short)f2b(a.z); o[3] = (short)f2b(a.w);
            o[4] = (short)f2b(c.x); o[5] = (short)f2b(c.y); o[6] = (short)f2b(c.z); o[7] = (short)f2b(c.w);
            ((bf16x8*)xb)[i] = o;
        }
        return;
    }
    const float* W = y ? W1 : W0;
    float* out = partials + y * 1024;
    __shared__ float sdata[256];
    float s = 0.f;
    const int stride = gridDim.x * blockDim.x;
    for (int i = blockIdx.x * blockDim.x + threadIdx.x; i < n4; i += stride) {
        float4 v = ((const float4*)W)[i];
        s += fabsf(v.x) + fabsf(v.y) + fabsf(v.z) + fabsf(v.w);
    }
    sdata[threadIdx.x] = s;
    __syncthreads();
    for (int off = 128; off > 0; off >>= 1) {
        if (threadIdx.x < off) sdata[threadIdx.x] += sdata[threadIdx.x + off];
        __syncthreads();
    }
    if (threadIdx.x == 0) out[blockIdx.x] = sdata[0];
}

__global__ void absmean_finalize2(const float* __restrict__ partials, float inv_n,
                                  float* __restrict__ gamma) {
    const float* p = partials + blockIdx.x * 1024;
    __shared__ float sdata[256];
    float s = 0.f;
    for (int i = threadIdx.x; i < 1024; i += 256) s += p[i];
    sdata[threadIdx.x] = s;
    __syncthreads();
    for (int off = 128; off > 0; off >>= 1) {
        if (threadIdx.x < off) sdata[threadIdx.x] += sdata[threadIdx.x + off];
        __syncthreads();
    }
    if (threadIdx.x == 0) gamma[blockIdx.x] = sdata[0] * inv_n + 1e-6f;
}

// ---------- prep2: quant W0 (y=0), quant W1 * lnw (y=1), GEMV c1/c0 (y=2) ----
__global__ void prep2(const float* __restrict__ W0, const float* __restrict__ W1,
                      const float* __restrict__ lnw, const float* __restrict__ lnb,
                      const float* __restrict__ gamma,
                      u16* __restrict__ Q0, u16* __restrict__ Q1,
                      float* __restrict__ c1, float* __restrict__ c0, int n4) {
    const int y = blockIdx.y;
    if (y == 2) {
        // c1[d] = sum_h lnw[h]*tern(W1[d,h]); c0[d] = sum_h lnb[h]*tern(W1[d,h])
        const float thr = 0.5f * gamma[1];
        const float* row = W1 + (size_t)blockIdx.x * D_HID;
        float s1 = 0.f, s0 = 0.f;
        for (int h = threadIdx.x; h < D_HID; h += 256) {
            float v = row[h];
            float t = v > thr ? 1.f : (v < -thr ? -1.f : 0.f);
            s1 += lnw[h] * t;
            s0 += lnb[h] * t;
        }
#pragma unroll
        for (int off = 32; off > 0; off >>= 1) {
            s1 += __shfl_down(s1, off);
            s0 += __shfl_down(s0, off);
        }
        __shared__ float sh1[4], sh0[4];
        const int wave = threadIdx.x >> 6, lane = threadIdx.x & 63;
        if (lane == 0) { sh1[wave] = s1; sh0[wave] = s0; }
        __syncthreads();
        if (threadIdx.x == 0) {
            c1[blockIdx.x] = sh1[0] + sh1[1] + sh1[2] + sh1[3];
            c0[blockIdx.x] = sh0[0] + sh0[1] + sh0[2] + sh0[3];
        }
        return;
    }
    const float* W = y ? W1 : W0;
    u16* Wq = y ? Q1 : Q0;
    const float thr = 0.5f * gamma[y];
    const int stride = gridDim.x * blockDim.x;
    for (int i = blockIdx.x * blockDim.x + threadIdx.x; i < n4; i += stride) {
        float4 v = ((const float4*)W)[i];
        ushort4 q;
        if (y == 0) {
            q.x = v.x > thr ? 0x3F80u : (v.x < -thr ? 0xBF80u : 0u);
            q.y = v.y > thr ? 0x3F80u : (v.y < -thr ? 0xBF80u : 0u);
            q.z = v.z > thr ? 0x3F80u : (v.z < -thr ? 0xBF80u : 0u);
            q.w = v.w > thr ? 0x3F80u : (v.w < -thr ? 0xBF80u : 0u);
        } else {
            // fold ln weight into ternary (exact for lnw=1)
            const int h = (i * 4) & (D_HID - 1);
            float w0 = lnw[h], w1 = lnw[h + 1], w2 = lnw[h + 2], w3 = lnw[h + 3];
            q.x = v.x > thr ? f2b(w0) : (v.x < -thr ? f2b(-w0) : 0u);
            q.y = v.y > thr ? f2b(w1) : (v.y < -thr ? f2b(-w1) : 0u);
            q.z = v.z > thr ? f2b(w2) : (v.z < -thr ? f2b(-w2) : 0u);
            q.w = v.w > thr ? f2b(w3) : (v.w < -thr ? f2b(-w3) : 0u);
        }
        ((ushort4*)Wq)[i] = q;
    }
}

// ---------- stats finalize: (sumG, sumG2) -> A=rstd, B=-mu*rstd ----------
__global__ void finalize_stats(const float* __restrict__ pS, const float* __restrict__ pSS,
                               float* __restrict__ stA, float* __restrict__ stB) {
    const int r = blockIdx.x * 256 + threadIdx.x;
    float s = 0.f, ss = 0.f;
#pragma unroll
    for (int b = 0; b < 16; ++b) { s += pS[b * MROWS + r]; ss += pSS[b * MROWS + r]; }
    const float mu = s * (1.f / (float)D_HID);
    const float var = ss * (1.f / (float)D_HID) - mu * mu;
    const float A = rsqrtf(var + 1e-5f);
    stA[r] = A;
    stB[r] = -mu * A;
}

// ==========================================================================
// 256x256 8-phase GEMM: C[M,N] = A[M,K] @ B[N,K]^T   (bf16 in)
// EPI 0: GELU epilogue, bf16 out + per-row (sumG,sumG2) partials -> pS/pSS.
// EPI 1: fused-LN epilogue: out = stA[row]*acc + stB[row]*c1[col] + c0[col].
// ==========================================================================
template <int EPI>
__global__ __launch_bounds__(512, 2)
void gemm256(const u16* __restrict__ A, const u16* __restrict__ B,
             void* __restrict__ Cout, int M, int N, int K, int nbx,
             float* __restrict__ pS, float* __restrict__ pSS,
             const float* __restrict__ stA, const float* __restrict__ stB,
             const float* __restrict__ c1t, const float* __restrict__ c0t)
{
    (void)M;
    __shared__ u16 lds[65536];           // 128 KiB
    char* const ldsc = (char*)lds;
    const int tid = threadIdx.x;
    const int w = tid >> 6, lane = tid & 63;

    // bijective XCD swizzle (nwg % 8 == 0 for our grids)
    const int nwg = (int)gridDim.x;
    const int qq = nwg >> 3;
    const int bid = (int)blockIdx.x;
    const int swz = (bid & 7) * qq + (bid >> 3);
    const int bx = swz % nbx, by = swz / nbx;
    const size_t m0 = (size_t)by * 256, n0 = (size_t)bx * 256;

    const int wm = (w >> 2) * 128;       // 0 or 128
    const int wn = (w & 3) * 64;         // 0,64,128,192

    // ---- staging constants: thread tid covers LDS bytes [tid*16,+16) of a half
    const int d0 = tid * 16;
    const int rrow = (d0 >> 6) & 15;
    const int sr0 = ((d0 >> 11) & 3) * 16 + rrow;                 // 0..63 (load1: +64)
    const int cbx = (d0 & 63) ^ (((rrow >> 3) & 1) << 5);         // inverse swizzle on source
    const int gc  = ((d0 >> 10) & 1) * 32 + (cbx >> 1);           // global element col 0..63

    // ---- fragment-read bases (swizzle folded into lane offset)
    const int laneoffsw = (((lane & 15) * 64) + ((lane >> 4) * 16)) ^ (((lane >> 3) & 1) << 5);
    const int aoff = ((wm >> 7) << 14) + laneoffsw;
    const int boff = 65536 + ((wn >> 7) << 14) + (((wn >> 4) & 7) << 11) + laneoffsw;

    f32x4 acc[8][4];
#pragma unroll
    for (int i = 0; i < 8; ++i)
#pragma unroll
        for (int j = 0; j < 4; ++j) acc[i][j] = (f32x4){0.f, 0.f, 0.f, 0.f};

    bf16x8 a[4][2], b[4][2];

#define STAGE_A(KT, BUFB, HH) do {                                                              \
    const u16* _s = A + (size_t)(m0 + (HH) * 128 + sr0) * K + (size_t)(KT) * 64 + gc;           \
    __builtin_amdgcn_global_load_lds((const __attribute__((address_space(1))) void*)_s,         \
        (__attribute__((address_space(3))) void*)(ldsc + (BUFB) * 32768 + (HH) * 16384 + w * 1024), 16, 0, 0); \
    __builtin_amdgcn_global_load_lds((const __attribute__((address_space(1))) void*)(_s + (size_t)64 * K), \
        (__attribute__((address_space(3))) void*)(ldsc + (BUFB) * 32768 + (HH) * 16384 + w * 1024 + 8192), 16, 0, 0); \
} while (0)

#define STAGE_B(KT, BUFB, HH) do {                                                              \
    const u16* _s = B + (size_t)(n0 + (HH) * 128 + sr0) * K + (size_t)(KT) * 64 + gc;           \
    __builtin_amdgcn_global_load_lds((const __attribute__((address_space(1))) void*)_s,         \
        (__attribute__((address_space(3))) void*)(ldsc + 65536 + (BUFB) * 32768 + (HH) * 16384 + w * 1024), 16, 0, 0); \
    __builtin_amdgcn_global_load_lds((const __attribute__((address_space(1))) void*)(_s + (size_t)64 * K), \
        (__attribute__((address_space(3))) void*)(ldsc + 65536 + (BUFB) * 32768 + (HH) * 16384 + w * 1024 + 8192), 16, 0, 0); \
} while (0)

#define RD_A(BUFB, S, KS) (*(const bf16x8*)(ldsc + (BUFB) * 32768 + aoff + ((S) << 11) + ((KS) << 10)))
#define RD_B(BUFB, S, KS) (*(const bf16x8*)(ldsc + (BUFB) * 32768 + boff + ((S) << 11) + ((KS) << 10)))

#define MM(MB, NB) do {                                                                         \
    _Pragma("unroll") for (int ii = 0; ii < 4; ++ii)                                            \
    _Pragma("unroll") for (int jj = 0; jj < 2; ++jj)                                            \
    _Pragma("unroll") for (int kk = 0; kk < 2; ++kk)                                            \
        acc[(MB) + ii][(NB) + jj] = __builtin_amdgcn_mfma_f32_16x16x32_bf16(                    \
            a[ii][kk], b[(NB) + jj][kk], acc[(MB) + ii][(NB) + jj], 0, 0, 0);                   \
} while (0)

#define BARR()  asm volatile("s_barrier" ::: "memory")
#define LGKM0() asm volatile("s_waitcnt lgkmcnt(0)" ::: "memory")

#define ITER(F) do {                                                                            \
    _Pragma("unroll") for (int s = 0; s < 4; ++s) { a[s][0] = RD_A(0, s, 0); a[s][1] = RD_A(0, s, 1); } \
    _Pragma("unroll") for (int s = 0; s < 2; ++s) { b[s][0] = RD_B(0, s, 0); b[s][1] = RD_B(0, s, 1); } \
    STAGE_A(t + 1, 1, 0);                                                                       \
    asm volatile("s_waitcnt lgkmcnt(8)" ::: "memory");                                          \
    BARR(); LGKM0();                                                                            \
    __builtin_amdgcn_s_setprio(1); MM(0, 0); __builtin_amdgcn_s_setprio(0); BARR();             \
    _Pragma("unroll") for (int s = 2; s < 4; ++s) { b[s][0] = RD_B(0, s, 0); b[s][1] = RD_B(0, s, 1); } \
    STAGE_A(t + 1, 1, 1);                                                                       \
    BARR(); LGKM0();                                                                            \
    __builtin_amdgcn_s_setprio(1); MM(0, 2); __builtin_amdgcn_s_setprio(0); BARR();             \
    _Pragma("unroll") for (int s = 0; s < 4; ++s) { a[s][0] = RD_A(0, 4 + s, 0); a[s][1] = RD_A(0, 4 + s, 1); } \
    if (F) STAGE_B(t + 2, 0, 0);                                                                \
    BARR(); LGKM0();                                                                            \
    __builtin_amdgcn_s_setprio(1); MM(4, 0); __builtin_amdgcn_s_setprio(0); BARR();             \
    if (F) { STAGE_B(t + 2, 0, 1); asm volatile("s_waitcnt vmcnt(4)" ::: "memory"); }           \
    else   { asm volatile("s_waitcnt vmcnt(0)" ::: "memory"); }                                 \
    BARR();                                                                                     \
    __builtin_amdgcn_s_setprio(1); MM(4, 2); __builtin_amdgcn_s_setprio(0); BARR();             \
    _Pragma("unroll") for (int s = 0; s < 4; ++s) { a[s][0] = RD_A(1, s, 0); a[s][1] = RD_A(1, s, 1); } \
    _Pragma("unroll") for (int s = 0; s < 2; ++s) { b[s][0] = RD_B(1, s, 0); b[s][1] = RD_B(1, s, 1); } \
    if (F) STAGE_A(t + 2, 0, 0);                                                                \
    asm volatile("s_waitcnt lgkmcnt(8)" ::: "memory");                                          \
    BARR(); LGKM0();                                                                            \
    __builtin_amdgcn_s_setprio(1); MM(0, 0); __builtin_amdgcn_s_setprio(0); BARR();             \
    _Pragma("unroll") for (int s = 2; s < 4; ++s) { b[s][0] = RD_B(1, s, 0); b[s][1] = RD_B(1, s, 1); } \
    if (F) STAGE_A(t + 2, 0, 1);                                                                \
    BARR(); LGKM0();                                                                            \
    __builtin_amdgcn_s_setprio(1); MM(0, 2); __builtin_amdgcn_s_setprio(0); BARR();             \
    _Pragma("unroll") for (int s = 0; s < 4; ++s) { a[s][0] = RD_A(1, 4 + s, 0); a[s][1] = RD_A(1, 4 + s, 1); } \
    if (F) STAGE_B(t + 3, 1, 0);                                                                \
    BARR(); LGKM0();                                                                            \
    __builtin_amdgcn_s_setprio(1); MM(4, 0); __builtin_amdgcn_s_setprio(0); BARR();             \
    if (F) { STAGE_B(t + 3, 1, 1); asm volatile("s_waitcnt vmcnt(4)" ::: "memory"); }           \
    BARR();                                                                                     \
    __builtin_amdgcn_s_setprio(1); MM(4, 2); __builtin_amdgcn_s_setprio(0); BARR();             \
} while (0)

    const int nkt = K >> 6;
    const int niter = nkt >> 1;

    STAGE_A(0, 0, 0);
    STAGE_A(0, 0, 1);
    STAGE_B(0, 0, 0);
    STAGE_B(0, 0, 1);
    STAGE_B(1, 1, 0);
    STAGE_B(1, 1, 1);
    asm volatile("s_waitcnt vmcnt(4)" ::: "memory");
    BARR();

    for (int it = 0; it + 1 < niter; ++it) { const int t = 2 * it; ITER(1); }
    { const int t = 2 * (niter - 1); ITER(0); }

    // ---- epilogue: C/D layout col = lane&15, row = (lane>>4)*4 + r
    const int fr = (lane >> 4) * 4;
    const int fc = lane & 15;
    if constexpr (EPI == 0) {
        // reuse staging LDS (all waves past final reads) for per-row reduction
        float* redS  = (float*)ldsc;            // [4][256]
        float* redSS = (float*)(ldsc + 4096);   // [4][256]
        const int wnq = w & 3;
        u16* C = (u16*)Cout;
#pragma unroll
        for (int mf = 0; mf < 8; ++mf)
#pragma unroll
            for (int r = 0; r < 4; ++r) {
                const int lrow = wm + mf * 16 + fr + r;
                const size_t row = m0 + lrow;
                float s = 0.f, ss = 0.f;
#pragma unroll
                for (int nf = 0; nf < 4; ++nf) {
                    float g = gelu_fast(acc[mf][nf][r]);
                    C[row * (size_t)N + (n0 + wn + nf * 16 + fc)] = f2b(g);
                    s += g;
                    ss = fmaf(g, g, ss);
                }
#pragma unroll
                for (int mask = 1; mask < 16; mask <<= 1) {
                    s  += __shfl_xor(s, mask);
                    ss += __shfl_xor(ss, mask);
                }
                if (fc == 0) { redS[wnq * 256 + lrow] = s; redSS[wnq * 256 + lrow] = ss; }
            }
        __syncthreads();
        if (tid < 256) {
            float s  = redS[tid]  + redS[256 + tid]  + redS[512 + tid]  + redS[768 + tid];
            float ss = redSS[tid] + redSS[256 + tid] + redSS[512 + tid] + redSS[768 + tid];
            pS[(size_t)bx * MROWS + m0 + tid]  = s;
            pSS[(size_t)bx * MROWS + m0 + tid] = ss;
        }
    } else {
        float* C = (float*)Cout;
        float c1v[4], c0v[4];
#pragma unroll
        for (int nf = 0; nf < 4; ++nf) {
            const size_t col = n0 + wn + nf * 16 + fc;
            c1v[nf] = c1t[col];
            c0v[nf] = c0t[col];
        }
#pragma unroll
        for (int mf = 0; mf < 8; ++mf)
#pragma unroll
            for (int r = 0; r < 4; ++r) {
                const size_t row = m0 + wm + mf * 16 + fr + r;
                const float Av = stA[row], Bv = stB[row];
#pragma unroll
                for (int nf = 0; nf < 4; ++nf) {
                    const size_t col = n0 + wn + nf * 16 + fc;
                    C[row * (size_t)N + col] = fmaf(Av, acc[mf][nf][r], fmaf(Bv, c1v[nf], c0v[nf]));
                }
            }
    }
#undef STAGE_A
#undef STAGE_B
#undef RD_A
#undef RD_B
#undef MM
#undef BARR
#undef LGKM0
#undef ITER
}

extern "C" void kernel_launch(void* const* d_in, const int* in_sizes, int n_in,
                              void* d_out, int out_size, void* d_ws, size_t ws_size,
                              hipStream_t stream)
{
    const float* x   = (const float*)d_in[0];
    const float* Wfc = (const float*)d_in[1];
    const float* lnw = (const float*)d_in[2];
    const float* lnb = (const float*)d_in[3];
    const float* Wpj = (const float*)d_in[4];
    float* out = (float*)d_out;
    char* ws = (char*)d_ws;

    u16* Wq_fc = (u16*)ws;                                   // 8 MiB
    u16* Wq_pj = (u16*)(ws + (size_t)(8u  << 20));           // 8 MiB (scaled by lnw)
    u16* xb    = (u16*)(ws + (size_t)(16u << 20));           // 32 MiB
    u16* hbuf  = (u16*)(ws + (size_t)(48u << 20));           // 128 MiB (post-GELU, pre-LN)
    char* tail = ws + (size_t)(176u << 20);
    float* parts = (float*)tail;                             // 2 x 1024
    float* gam   = (float*)(tail + 8192);                    // 2
    float* stA   = (float*)(tail + 16384);                   // 16384
    float* stB   = (float*)(tail + 16384 + 65536);           // 16384
    float* c1t   = (float*)(tail + 16384 + 131072);          // 1024
    float* c0t   = (float*)(tail + 16384 + 131072 + 4096);   // 1024
    float* pS    = (float*)(ws + (size_t)(177u << 20));      // 16 x 16384 (1 MiB)
    float* pSS   = (float*)(ws + (size_t)(178u << 20));      // 16 x 16384 (1 MiB)

    const int nW  = D_HID * D_IN;        // 4,194,304
    const int nW4 = nW / 4;
    const int nX8 = MROWS * D_IN / 8;    // 2,097,152

    // prep: absmean partials (y=0,1) + x->bf16 cast (y=2)
    prep1<<<dim3(1024, 3), 256, 0, stream>>>(x, Wfc, Wpj, xb, parts, nW4, nX8);
    absmean_finalize2<<<2, 256, 0, stream>>>(parts, 1.f / (float)nW, gam);
    // quant both weights (Wpj folded with lnw) + GEMV for c1/c0
    prep2<<<dim3(1024, 3), 256, 0, stream>>>(Wfc, Wpj, lnw, lnb, gam, Wq_fc, Wq_pj, c1t, c0t, nW4);

    // GEMM1: [16384,1024] x [4096,1024]^T -> GELU -> bf16 + row stats partials
    {
        const int nbx = D_HID / 256;     // 16
        const int nby = MROWS / 256;     // 64
        gemm256<0><<<dim3(nbx * nby), dim3(512), 0, stream>>>(
            xb, Wq_fc, hbuf, MROWS, D_HID, D_IN, nbx, pS, pSS, nullptr, nullptr, nullptr, nullptr);
    }

    finalize_stats<<<64, 256, 0, stream>>>(pS, pSS, stA, stB);

    // GEMM2: [16384,4096] x [1024,4096]^T with fused LayerNorm epilogue -> f32
    {
        const int nbx = D_IN / 256;      // 4
        const int nby = MROWS / 256;     // 64
        gemm256<1><<<dim3(nbx * nby), dim3(512), 0, stream>>>(
            hbuf, Wq_pj, out, MROWS, D_IN, D_HID, nbx, nullptr, nullptr, stA, stB, c1t, c0t);
    }
}

// Round 11
// 403.484 us; speedup vs baseline: 1.4889x; 1.0189x over previous
//
#include <hip/hip_runtime.h>
#include <hip/hip_bf16.h>

typedef __attribute__((ext_vector_type(8))) short bf16x8;
typedef __attribute__((ext_vector_type(4))) float f32x4;
typedef unsigned short u16;

#define D_IN  1024
#define D_HID 4096
#define MROWS 16384   // B*T = 8*2048

// ---------- bf16 <-> f32 helpers (bit-exact RNE) ----------
__device__ __forceinline__ float b2f(u16 u) {
    union { unsigned int i; float f; } c; c.i = ((unsigned int)u) << 16; return c.f;
}
__device__ __forceinline__ u16 f2b(float f) {
    unsigned int u = __builtin_bit_cast(unsigned int, f);
    return (u16)((u + 0x7FFFu + ((u >> 16) & 1u)) >> 16);
}

// ---------- fast branchless GELU (tanh form, err<=3e-3 abs, << bf16 step) ----
__device__ __forceinline__ float gelu_fast(float v) {
    float p = v * fmaf(0.044715f * v, v, 1.0f);
    float e = __builtin_amdgcn_exp2f(-2.302202983f * p);
    return v * __builtin_amdgcn_rcpf(1.0f + e);
}

// ---------- 16-lane (DPP row) sum via row_shr: TOTAL lands in lane&15==15 ----
__device__ __forceinline__ float rowsum16(float v) {
    int t;
    t = __builtin_amdgcn_update_dpp(0, __builtin_bit_cast(int, v), 0x111, 0xf, 0xf, true);
    v += __builtin_bit_cast(float, t);
    t = __builtin_amdgcn_update_dpp(0, __builtin_bit_cast(int, v), 0x112, 0xf, 0xf, true);
    v += __builtin_bit_cast(float, t);
    t = __builtin_amdgcn_update_dpp(0, __builtin_bit_cast(int, v), 0x114, 0xf, 0xf, true);
    v += __builtin_bit_cast(float, t);
    t = __builtin_amdgcn_update_dpp(0, __builtin_bit_cast(int, v), 0x118, 0xf, 0xf, true);
    v += __builtin_bit_cast(float, t);
    return v;   // lane i holds sum of lanes (rowbase..i); lane 15 holds full row sum
}

// ---------- prep1: absmean partials for both W (y=0,1) + cast x->bf16 (y=2) ----
__global__ void prep1(const float* __restrict__ x, const float* __restrict__ W0,
                      const float* __restrict__ W1, u16* __restrict__ xb,
                      float* __restrict__ partials, int n4, int n8) {
    const int y = blockIdx.y;
    if (y == 2) {
        const int stride = gridDim.x * blockDim.x;
        for (int i = blockIdx.x * blockDim.x + threadIdx.x; i < n8; i += stride) {
            float4 a = ((const float4*)x)[2 * i];
            float4 c = ((const float4*)x)[2 * i + 1];
            bf16x8 o;
            o[0] = (short)f2b(a.x); o[1] = (short)f2b(a.y); o[2] = (short)f2b(a.z); o[3] = (short)f2b(a.w);
            o[4] = (short)f2b(c.x); o[5] = (short)f2b(c.y); o[6] = (short)f2b(c.z); o[7] = (short)f2b(c.w);
            ((bf16x8*)xb)[i] = o;
        }
        return;
    }
    const float* W = y ? W1 : W0;
    float* out = partials + y * 1024;
    __shared__ float sdata[256];
    float s = 0.f;
    const int stride = gridDim.x * blockDim.x;
    for (int i = blockIdx.x * blockDim.x + threadIdx.x; i < n4; i += stride) {
        float4 v = ((const float4*)W)[i];
        s += fabsf(v.x) + fabsf(v.y) + fabsf(v.z) + fabsf(v.w);
    }
    sdata[threadIdx.x] = s;
    __syncthreads();
    for (int off = 128; off > 0; off >>= 1) {
        if (threadIdx.x < off) sdata[threadIdx.x] += sdata[threadIdx.x + off];
        __syncthreads();
    }
    if (threadIdx.x == 0) out[blockIdx.x] = sdata[0];
}

__global__ void absmean_finalize2(const float* __restrict__ partials, float inv_n,
                                  float* __restrict__ gamma) {
    const float* p = partials + blockIdx.x * 1024;
    __shared__ float sdata[256];
    float s = 0.f;
    for (int i = threadIdx.x; i < 1024; i += 256) s += p[i];
    sdata[threadIdx.x] = s;
    __syncthreads();
    for (int off = 128; off > 0; off >>= 1) {
        if (threadIdx.x < off) sdata[threadIdx.x] += sdata[threadIdx.x + off];
        __syncthreads();
    }
    if (threadIdx.x == 0) gamma[blockIdx.x] = sdata[0] * inv_n + 1e-6f;
}

// ---------- prep2: quant W0 (y=0), quant W1 * lnw (y=1), GEMV c1/c0 (y=2) ----
__global__ void prep2(const float* __restrict__ W0, const float* __restrict__ W1,
                      const float* __restrict__ lnw, const float* __restrict__ lnb,
                      const float* __restrict__ gamma,
                      u16* __restrict__ Q0, u16* __restrict__ Q1,
                      float* __restrict__ c1, float* __restrict__ c0, int n4) {
    const int y = blockIdx.y;
    if (y == 2) {
        // c1[d] = sum_h lnw[h]*tern(W1[d,h]); c0[d] = sum_h lnb[h]*tern(W1[d,h])
        const float thr = 0.5f * gamma[1];
        const float* row = W1 + (size_t)blockIdx.x * D_HID;
        float s1 = 0.f, s0 = 0.f;
        for (int h = threadIdx.x; h < D_HID; h += 256) {
            float v = row[h];
            float t = v > thr ? 1.f : (v < -thr ? -1.f : 0.f);
            s1 += lnw[h] * t;
            s0 += lnb[h] * t;
        }
#pragma unroll
        for (int off = 32; off > 0; off >>= 1) {
            s1 += __shfl_down(s1, off);
            s0 += __shfl_down(s0, off);
        }
        __shared__ float sh1[4], sh0[4];
        const int wave = threadIdx.x >> 6, lane = threadIdx.x & 63;
        if (lane == 0) { sh1[wave] = s1; sh0[wave] = s0; }
        __syncthreads();
        if (threadIdx.x == 0) {
            c1[blockIdx.x] = sh1[0] + sh1[1] + sh1[2] + sh1[3];
            c0[blockIdx.x] = sh0[0] + sh0[1] + sh0[2] + sh0[3];
        }
        return;
    }
    const float* W = y ? W1 : W0;
    u16* Wq = y ? Q1 : Q0;
    const float thr = 0.5f * gamma[y];
    const int stride = gridDim.x * blockDim.x;
    for (int i = blockIdx.x * blockDim.x + threadIdx.x; i < n4; i += stride) {
        float4 v = ((const float4*)W)[i];
        ushort4 q;
        if (y == 0) {
            q.x = v.x > thr ? 0x3F80u : (v.x < -thr ? 0xBF80u : 0u);
            q.y = v.y > thr ? 0x3F80u : (v.y < -thr ? 0xBF80u : 0u);
            q.z = v.z > thr ? 0x3F80u : (v.z < -thr ? 0xBF80u : 0u);
            q.w = v.w > thr ? 0x3F80u : (v.w < -thr ? 0xBF80u : 0u);
        } else {
            // fold ln weight into ternary (exact for lnw=1)
            const int h = (i * 4) & (D_HID - 1);
            float w0 = lnw[h], w1 = lnw[h + 1], w2 = lnw[h + 2], w3 = lnw[h + 3];
            q.x = v.x > thr ? f2b(w0) : (v.x < -thr ? f2b(-w0) : 0u);
            q.y = v.y > thr ? f2b(w1) : (v.y < -thr ? f2b(-w1) : 0u);
            q.z = v.z > thr ? f2b(w2) : (v.z < -thr ? f2b(-w2) : 0u);
            q.w = v.w > thr ? f2b(w3) : (v.w < -thr ? f2b(-w3) : 0u);
        }
        ((ushort4*)Wq)[i] = q;
    }
}

// ==========================================================================
// 256x256 8-phase GEMM: C[M,N] = A[M,K] @ B[N,K]^T   (bf16 in)
// EPI 0: GELU epilogue, bf16 out + per-row (sumG,sumG2) partials via DPP
//        rowsum (total in lane&15==15) + 8KB LDS quadrant fold -> pS/pSS.
// EPI 1: fused-LN epilogue; per-row stats computed in-block from pS/pSS:
//        out = rstd*acc + (-mu*rstd)*c1[col] + c0[col].
// ==========================================================================
template <int EPI>
__global__ __launch_bounds__(512, 2)
void gemm256(const u16* __restrict__ A, const u16* __restrict__ B,
             void* __restrict__ Cout, int M, int N, int K, int nbx,
             float* __restrict__ pS, float* __restrict__ pSS,
             const float* __restrict__ c1t, const float* __restrict__ c0t)
{
    (void)M;
    __shared__ u16 lds[65536];           // 128 KiB
    char* const ldsc = (char*)lds;
    const int tid = threadIdx.x;
    const int w = tid >> 6, lane = tid & 63;

    // bijective XCD swizzle (nwg % 8 == 0 for our grids)
    const int nwg = (int)gridDim.x;
    const int qq = nwg >> 3;
    const int bid = (int)blockIdx.x;
    const int swz = (bid & 7) * qq + (bid >> 3);
    const int bx = swz % nbx, by = swz / nbx;
    const size_t m0 = (size_t)by * 256, n0 = (size_t)bx * 256;

    const int wm = (w >> 2) * 128;       // 0 or 128
    const int wn = (w & 3) * 64;         // 0,64,128,192

    // ---- staging constants: thread tid covers LDS bytes [tid*16,+16) of a half
    const int d0 = tid * 16;
    const int rrow = (d0 >> 6) & 15;
    const int sr0 = ((d0 >> 11) & 3) * 16 + rrow;                 // 0..63 (load1: +64)
    const int cbx = (d0 & 63) ^ (((rrow >> 3) & 1) << 5);         // inverse swizzle on source
    const int gc  = ((d0 >> 10) & 1) * 32 + (cbx >> 1);           // global element col 0..63

    // ---- fragment-read bases (swizzle folded into lane offset)
    const int laneoffsw = (((lane & 15) * 64) + ((lane >> 4) * 16)) ^ (((lane >> 3) & 1) << 5);
    const int aoff = ((wm >> 7) << 14) + laneoffsw;
    const int boff = 65536 + ((wn >> 7) << 14) + (((wn >> 4) & 7) << 11) + laneoffsw;

    f32x4 acc[8][4];
#pragma unroll
    for (int i = 0; i < 8; ++i)
#pragma unroll
        for (int j = 0; j < 4; ++j) acc[i][j] = (f32x4){0.f, 0.f, 0.f, 0.f};

    bf16x8 a[4][2], b[4][2];

#define STAGE_A(KT, BUFB, HH) do {                                                              \
    const u16* _s = A + (size_t)(m0 + (HH) * 128 + sr0) * K + (size_t)(KT) * 64 + gc;           \
    __builtin_amdgcn_global_load_lds((const __attribute__((address_space(1))) void*)_s,         \
        (__attribute__((address_space(3))) void*)(ldsc + (BUFB) * 32768 + (HH) * 16384 + w * 1024), 16, 0, 0); \
    __builtin_amdgcn_global_load_lds((const __attribute__((address_space(1))) void*)(_s + (size_t)64 * K), \
        (__attribute__((address_space(3))) void*)(ldsc + (BUFB) * 32768 + (HH) * 16384 + w * 1024 + 8192), 16, 0, 0); \
} while (0)

#define STAGE_B(KT, BUFB, HH) do {                                                              \
    const u16* _s = B + (size_t)(n0 + (HH) * 128 + sr0) * K + (size_t)(KT) * 64 + gc;           \
    __builtin_amdgcn_global_load_lds((const __attribute__((address_space(1))) void*)_s,         \
        (__attribute__((address_space(3))) void*)(ldsc + 65536 + (BUFB) * 32768 + (HH) * 16384 + w * 1024), 16, 0, 0); \
    __builtin_amdgcn_global_load_lds((const __attribute__((address_space(1))) void*)(_s + (size_t)64 * K), \
        (__attribute__((address_space(3))) void*)(ldsc + 65536 + (BUFB) * 32768 + (HH) * 16384 + w * 1024 + 8192), 16, 0, 0); \
} while (0)

#define RD_A(BUFB, S, KS) (*(const bf16x8*)(ldsc + (BUFB) * 32768 + aoff + ((S) << 11) + ((KS) << 10)))
#define RD_B(BUFB, S, KS) (*(const bf16x8*)(ldsc + (BUFB) * 32768 + boff + ((S) << 11) + ((KS) << 10)))

#define MM(MB, NB) do {                                                                         \
    _Pragma("unroll") for (int ii = 0; ii < 4; ++ii)                                            \
    _Pragma("unroll") for (int jj = 0; jj < 2; ++jj)                                            \
    _Pragma("unroll") for (int kk = 0; kk < 2; ++kk)                                            \
        acc[(MB) + ii][(NB) + jj] = __builtin_amdgcn_mfma_f32_16x16x32_bf16(                    \
            a[ii][kk], b[(NB) + jj][kk], acc[(MB) + ii][(NB) + jj], 0, 0, 0);                   \
} while (0)

#define BARR()  asm volatile("s_barrier" ::: "memory")
#define LGKM0() asm volatile("s_waitcnt lgkmcnt(0)" ::: "memory")

#define ITER(F) do {                                                                            \
    _Pragma("unroll") for (int s = 0; s < 4; ++s) { a[s][0] = RD_A(0, s, 0); a[s][1] = RD_A(0, s, 1); } \
    _Pragma("unroll") for (int s = 0; s < 2; ++s) { b[s][0] = RD_B(0, s, 0); b[s][1] = RD_B(0, s, 1); } \
    STAGE_A(t + 1, 1, 0);                                                                       \
    asm volatile("s_waitcnt lgkmcnt(8)" ::: "memory");                                          \
    BARR(); LGKM0();                                                                            \
    __builtin_amdgcn_s_setprio(1); MM(0, 0); __builtin_amdgcn_s_setprio(0); BARR();             \
    _Pragma("unroll") for (int s = 2; s < 4; ++s) { b[s][0] = RD_B(0, s, 0); b[s][1] = RD_B(0, s, 1); } \
    STAGE_A(t + 1, 1, 1);                                                                       \
    BARR(); LGKM0();                                                                            \
    __builtin_amdgcn_s_setprio(1); MM(0, 2); __builtin_amdgcn_s_setprio(0); BARR();             \
    _Pragma("unroll") for (int s = 0; s < 4; ++s) { a[s][0] = RD_A(0, 4 + s, 0); a[s][1] = RD_A(0, 4 + s, 1); } \
    if (F) STAGE_B(t + 2, 0, 0);                                                                \
    BARR(); LGKM0();                                                                            \
    __builtin_amdgcn_s_setprio(1); MM(4, 0); __builtin_amdgcn_s_setprio(0); BARR();             \
    if (F) { STAGE_B(t + 2, 0, 1); asm volatile("s_waitcnt vmcnt(4)" ::: "memory"); }           \
    else   { asm volatile("s_waitcnt vmcnt(0)" ::: "memory"); }                                 \
    BARR();                                                                                     \
    __builtin_amdgcn_s_setprio(1); MM(4, 2); __builtin_amdgcn_s_setprio(0); BARR();             \
    _Pragma("unroll") for (int s = 0; s < 4; ++s) { a[s][0] = RD_A(1, s, 0); a[s][1] = RD_A(1, s, 1); } \
    _Pragma("unroll") for (int s = 0; s < 2; ++s) { b[s][0] = RD_B(1, s, 0); b[s][1] = RD_B(1, s, 1); } \
    if (F) STAGE_A(t + 2, 0, 0);                                                                \
    asm volatile("s_waitcnt lgkmcnt(8)" ::: "memory");                                          \
    BARR(); LGKM0();                                                                            \
    __builtin_amdgcn_s_setprio(1); MM(0, 0); __builtin_amdgcn_s_setprio(0); BARR();             \
    _Pragma("unroll") for (int s = 2; s < 4; ++s) { b[s][0] = RD_B(1, s, 0); b[s][1] = RD_B(1, s, 1); } \
    if (F) STAGE_A(t + 2, 0, 1);                                                                \
    BARR(); LGKM0();                                                                            \
    __builtin_amdgcn_s_setprio(1); MM(0, 2); __builtin_amdgcn_s_setprio(0); BARR();             \
    _Pragma("unroll") for (int s = 0; s < 4; ++s) { a[s][0] = RD_A(1, 4 + s, 0); a[s][1] = RD_A(1, 4 + s, 1); } \
    if (F) STAGE_B(t + 3, 1, 0);                                                                \
    BARR(); LGKM0();                                                                            \
    __builtin_amdgcn_s_setprio(1); MM(4, 0); __builtin_amdgcn_s_setprio(0); BARR();             \
    if (F) { STAGE_B(t + 3, 1, 1); asm volatile("s_waitcnt vmcnt(4)" ::: "memory"); }           \
    BARR();                                                                                     \
    __builtin_amdgcn_s_setprio(1); MM(4, 2); __builtin_amdgcn_s_setprio(0); BARR();             \
} while (0)

    const int nkt = K >> 6;
    const int niter = nkt >> 1;

    STAGE_A(0, 0, 0);
    STAGE_A(0, 0, 1);
    STAGE_B(0, 0, 0);
    STAGE_B(0, 0, 1);
    STAGE_B(1, 1, 0);
    STAGE_B(1, 1, 1);
    asm volatile("s_waitcnt vmcnt(4)" ::: "memory");
    BARR();

    for (int it = 0; it + 1 < niter; ++it) { const int t = 2 * it; ITER(1); }
    { const int t = 2 * (niter - 1); ITER(0); }

    // ---- epilogue: C/D layout col = lane&15, row = (lane>>4)*4 + r
    const int fr = (lane >> 4) * 4;
    const int fc = lane & 15;
    if constexpr (EPI == 0) {
        // per-row (sumG, sumG2): DPP rowsum -> total in fc==15; that lane writes
        float2* qd = (float2*)ldsc;             // [256 rows][4 quadrants]
        const int wnq = w & 3;
        u16* C = (u16*)Cout;
#pragma unroll
        for (int mf = 0; mf < 8; ++mf)
#pragma unroll
            for (int r = 0; r < 4; ++r) {
                const int lrow = wm + mf * 16 + fr + r;
                const size_t row = m0 + lrow;
                float s = 0.f, ss = 0.f;
#pragma unroll
                for (int nf = 0; nf < 4; ++nf) {
                    float g = gelu_fast(acc[mf][nf][r]);
                    C[row * (size_t)N + (n0 + wn + nf * 16 + fc)] = f2b(g);
                    s += g;
                    ss = fmaf(g, g, ss);
                }
                s  = rowsum16(s);
                ss = rowsum16(ss);
                if (fc == 15) qd[lrow * 4 + wnq] = make_float2(s, ss);   // row_shr total lives in lane 15
            }
        __syncthreads();
        if (tid < 256) {
            float2 q0 = qd[tid * 4 + 0], q1 = qd[tid * 4 + 1];
            float2 q2 = qd[tid * 4 + 2], q3 = qd[tid * 4 + 3];
            pS[(size_t)bx * MROWS + m0 + tid]  = (q0.x + q1.x) + (q2.x + q3.x);
            pSS[(size_t)bx * MROWS + m0 + tid] = (q0.y + q1.y) + (q2.y + q3.y);
        }
    } else {
        // per-row LN stats computed in-block from GEMM1's partials
        float* sA = (float*)ldsc;               // [256] rstd
        float* sB = (float*)(ldsc + 1024);      // [256] -mu*rstd
        if (tid < 256) {
            float s = 0.f, ss = 0.f;
#pragma unroll
            for (int bq = 0; bq < 16; ++bq) {
                s  += pS[(size_t)bq * MROWS + m0 + tid];
                ss += pSS[(size_t)bq * MROWS + m0 + tid];
            }
            const float mu  = s * (1.f / (float)D_HID);
            const float var = ss * (1.f / (float)D_HID) - mu * mu;
            const float Av  = rsqrtf(var + 1e-5f);
            sA[tid] = Av;
            sB[tid] = -mu * Av;
        }
        __syncthreads();
        float* C = (float*)Cout;
        float c1v[4], c0v[4];
#pragma unroll
        for (int nf = 0; nf < 4; ++nf) {
            const size_t col = n0 + wn + nf * 16 + fc;
            c1v[nf] = c1t[col];
            c0v[nf] = c0t[col];
        }
#pragma unroll
        for (int mf = 0; mf < 8; ++mf)
#pragma unroll
            for (int r = 0; r < 4; ++r) {
                const int lrow = wm + mf * 16 + fr + r;
                const size_t row = m0 + lrow;
                const float Av = sA[lrow], Bv = sB[lrow];
#pragma unroll
                for (int nf = 0; nf < 4; ++nf) {
                    const size_t col = n0 + wn + nf * 16 + fc;
                    C[row * (size_t)N + col] = fmaf(Av, acc[mf][nf][r], fmaf(Bv, c1v[nf], c0v[nf]));
                }
            }
    }
#undef STAGE_A
#undef STAGE_B
#undef RD_A
#undef RD_B
#undef MM
#undef BARR
#undef LGKM0
#undef ITER
}

extern "C" void kernel_launch(void* const* d_in, const int* in_sizes, int n_in,
                              void* d_out, int out_size, void* d_ws, size_t ws_size,
                              hipStream_t stream)
{
    const float* x   = (const float*)d_in[0];
    const float* Wfc = (const float*)d_in[1];
    const float* lnw = (const float*)d_in[2];
    const float* lnb = (const float*)d_in[3];
    const float* Wpj = (const float*)d_in[4];
    float* out = (float*)d_out;
    char* ws = (char*)d_ws;

    u16* Wq_fc = (u16*)ws;                                   // 8 MiB
    u16* Wq_pj = (u16*)(ws + (size_t)(8u  << 20));           // 8 MiB (scaled by lnw)
    u16* xb    = (u16*)(ws + (size_t)(16u << 20));           // 32 MiB
    u16* hbuf  = (u16*)(ws + (size_t)(48u << 20));           // 128 MiB (post-GELU, pre-LN)
    char* tail = ws + (size_t)(176u << 20);
    float* parts = (float*)tail;                             // 2 x 1024
    float* gam   = (float*)(tail + 8192);                    // 2
    float* c1t   = (float*)(tail + 16384);                   // 1024
    float* c0t   = (float*)(tail + 16384 + 4096);            // 1024
    float* pS    = (float*)(ws + (size_t)(177u << 20));      // 16 x 16384 (1 MiB)
    float* pSS   = (float*)(ws + (size_t)(178u << 20));      // 16 x 16384 (1 MiB)

    const int nW  = D_HID * D_IN;        // 4,194,304
    const int nW4 = nW / 4;
    const int nX8 = MROWS * D_IN / 8;    // 2,097,152

    // prep: absmean partials (y=0,1) + x->bf16 cast (y=2)
    prep1<<<dim3(1024, 3), 256, 0, stream>>>(x, Wfc, Wpj, xb, parts, nW4, nX8);
    absmean_finalize2<<<2, 256, 0, stream>>>(parts, 1.f / (float)nW, gam);
    // quant both weights (Wpj folded with lnw) + GEMV for c1/c0
    prep2<<<dim3(1024, 3), 256, 0, stream>>>(Wfc, Wpj, lnw, lnb, gam, Wq_fc, Wq_pj, c1t, c0t, nW4);

    // GEMM1: [16384,1024] x [4096,1024]^T -> GELU -> bf16 + row stats partials
    {
        const int nbx = D_HID / 256;     // 16
        const int nby = MROWS / 256;     // 64
        gemm256<0><<<dim3(nbx * nby), dim3(512), 0, stream>>>(
            xb, Wq_fc, hbuf, MROWS, D_HID, D_IN, nbx, pS, pSS, nullptr, nullptr);
    }

    // GEMM2: [16384,4096] x [1024,4096]^T, LN fused (stats from pS/pSS) -> f32
    {
        const int nbx = D_IN / 256;      // 4
        const int nby = MROWS / 256;     // 64
        gemm256<1><<<dim3(nbx * nby), dim3(512), 0, stream>>>(
            hbuf, Wq_pj, out, MROWS, D_IN, D_HID, nbx, pS, pSS, c1t, c0t);
    }
}